// Round 8
// baseline (2842.733 us; speedup 1.0000x reference)
//
#include <hip/hip_runtime.h>

#define NN 50000
#define NE 800000
#define DIM 128
#define NB ((NN + 255) / 256)   // 196 scan chunks

// ================= CSR build (edge pattern reused for all 3 layers) =================
__global__ __launch_bounds__(256) void edge_histo(const int* __restrict__ ei,
                                                  int* __restrict__ cnt) {
  int e = blockIdx.x * 256 + threadIdx.x;
  if (e >= NE) return;
  int r = ei[e], c = ei[NE + e];
  if ((unsigned)r < NN && (unsigned)c < NN) atomicAdd(&cnt[r], 1);
}

// ---- distributed 2-level exclusive scan ----
__global__ __launch_bounds__(256) void block_sums(const int* __restrict__ cnt,
                                                  int* __restrict__ bsum) {
  int i = blockIdx.x * 256 + threadIdx.x;
  int v = (i < NN) ? cnt[i] : 0;
#pragma unroll
  for (int off = 1; off < 64; off <<= 1) v += __shfl_xor(v, off, 64);
  __shared__ int ws[4];
  if ((threadIdx.x & 63) == 0) ws[threadIdx.x >> 6] = v;
  __syncthreads();
  if (threadIdx.x == 0) bsum[blockIdx.x] = ws[0] + ws[1] + ws[2] + ws[3];
}

__global__ __launch_bounds__(256) void scan_bsums(const int* __restrict__ bsum,
                                                  int* __restrict__ bbase) {
  int t = threadIdx.x;
  int v = (t < NB) ? bsum[t] : 0;
  int lane = t & 63, w = t >> 6;
  int inc = v;
#pragma unroll
  for (int off = 1; off < 64; off <<= 1) {
    int u = __shfl_up(inc, off, 64);
    if (lane >= off) inc += u;
  }
  __shared__ int ws[4];
  if (lane == 63) ws[w] = inc;
  __syncthreads();
  int wb = 0;
  for (int k = 0; k < w; ++k) wb += ws[k];
  if (t < NB) bbase[t] = wb + inc - v;
}

__global__ __launch_bounds__(256) void scan_final(const int* __restrict__ cnt,
                                                  const int* __restrict__ bbase,
                                                  int* __restrict__ rowStart,
                                                  int* __restrict__ cursor) {
  int i = blockIdx.x * 256 + threadIdx.x;
  int v = (i < NN) ? cnt[i] : 0;
  int lane = threadIdx.x & 63, w = threadIdx.x >> 6;
  int inc = v;
#pragma unroll
  for (int off = 1; off < 64; off <<= 1) {
    int u = __shfl_up(inc, off, 64);
    if (lane >= off) inc += u;
  }
  __shared__ int ws[4];
  if (lane == 63) ws[w] = inc;
  __syncthreads();
  int wb = 0;
  for (int k = 0; k < w; ++k) wb += ws[k];
  int ex = bbase[blockIdx.x] + wb + inc - v;   // global exclusive prefix
  if (i < NN) { rowStart[i] = ex; cursor[i] = ex; }
  if (i == NN - 1) rowStart[NN] = ex + v;
}

// Scatter packed (col, val) into row-sorted order.
__global__ __launch_bounds__(256) void edge_scatter(const int* __restrict__ ei,
                                                    const float* __restrict__ vals,
                                                    int* __restrict__ cursor,
                                                    int2* __restrict__ cv) {
  int e = blockIdx.x * 256 + threadIdx.x;
  if (e >= NE) return;
  int r = ei[e], c = ei[NE + e];
  if ((unsigned)r >= NN || (unsigned)c >= NN) return;
  int pos = atomicAdd(&cursor[r], 1);
  cv[pos] = make_int2(c, __float_as_int(vals[e]));
}

// ============ SpMM gather: D/4 lanes per row, regs accumulate, no atomics ============
template <int D, bool BIAS>
__global__ __launch_bounds__(256) void spmm_csr(const int* __restrict__ rowStart,
                                                const int2* __restrict__ cv,
                                                const float* __restrict__ h,
                                                const float* __restrict__ bias,
                                                float* __restrict__ out) {
  constexpr int L = D / 4;                      // lanes per row
  const int lane = threadIdx.x % L;
  const int r = blockIdx.x * (256 / L) + threadIdx.x / L;
  if (r >= NN) return;
  int p = rowStart[r], pend = rowStart[r + 1];
  float4 acc = BIAS ? ((const float4*)bias)[lane] : make_float4(0.f, 0.f, 0.f, 0.f);
  for (; p + 3 < pend; p += 4) {
    int2 e0 = cv[p], e1 = cv[p + 1], e2 = cv[p + 2], e3 = cv[p + 3];
    float4 x0 = ((const float4*)(h + (size_t)e0.x * D))[lane];
    float4 x1 = ((const float4*)(h + (size_t)e1.x * D))[lane];
    float4 x2 = ((const float4*)(h + (size_t)e2.x * D))[lane];
    float4 x3 = ((const float4*)(h + (size_t)e3.x * D))[lane];
    float v0 = __int_as_float(e0.y), v1 = __int_as_float(e1.y);
    float v2 = __int_as_float(e2.y), v3 = __int_as_float(e3.y);
    acc.x = fmaf(v0, x0.x, acc.x); acc.y = fmaf(v0, x0.y, acc.y);
    acc.z = fmaf(v0, x0.z, acc.z); acc.w = fmaf(v0, x0.w, acc.w);
    acc.x = fmaf(v1, x1.x, acc.x); acc.y = fmaf(v1, x1.y, acc.y);
    acc.z = fmaf(v1, x1.z, acc.z); acc.w = fmaf(v1, x1.w, acc.w);
    acc.x = fmaf(v2, x2.x, acc.x); acc.y = fmaf(v2, x2.y, acc.y);
    acc.z = fmaf(v2, x2.z, acc.z); acc.w = fmaf(v2, x2.w, acc.w);
    acc.x = fmaf(v3, x3.x, acc.x); acc.y = fmaf(v3, x3.y, acc.y);
    acc.z = fmaf(v3, x3.z, acc.z); acc.w = fmaf(v3, x3.w, acc.w);
  }
  for (; p < pend; ++p) {
    int2 e0 = cv[p];
    float v0 = __int_as_float(e0.y);
    float4 x0 = ((const float4*)(h + (size_t)e0.x * D))[lane];
    acc.x = fmaf(v0, x0.x, acc.x); acc.y = fmaf(v0, x0.y, acc.y);
    acc.z = fmaf(v0, x0.z, acc.z); acc.w = fmaf(v0, x0.w, acc.w);
  }
  ((float4*)(out + (size_t)r * D))[lane] = acc;
}

// ---------------- fallback: atomic scatter SpMM (if ws too small) ----------------
__global__ __launch_bounds__(256) void spmm_atomic(
    const int* __restrict__ ei, const float* __restrict__ vals,
    const float* __restrict__ h, float* __restrict__ prop) {
  const int lane32 = threadIdx.x & 31;
  int hw = blockIdx.x * (blockDim.x >> 5) + (threadIdx.x >> 5);
  const int stride = gridDim.x * (blockDim.x >> 5);
  for (int e = hw; e < NE; e += stride) {
    int r = ei[e], c = ei[NE + e];
    float v = vals[e];
    if ((unsigned)r >= NN || (unsigned)c >= NN) continue;
    float4 x = ((const float4*)(h + (size_t)c * DIM))[lane32];
    float* pp = prop + (size_t)r * DIM + lane32 * 4;
    unsafeAtomicAdd(pp + 0, v * x.x);
    unsafeAtomicAdd(pp + 1, v * x.y);
    unsafeAtomicAdd(pp + 2, v * x.z);
    unsafeAtomicAdd(pp + 3, v * x.w);
  }
}

// ========== Register-tiled dense layer with explicit depth-1 register prefetch ==========
// Round-7 counters: VGPR=36 => compiler serialized the load window (VALUBusy 23%).
// Fix: next chunk's 8 dwordx4 loads are issued into named regs BEFORE current chunk's
// 64 FMAs; full unroll renames the rotation. Forces ~95 live VGPRs (cap 128 via (256,4)).
template <int OUT_DIM, int MR, bool NORM, bool BIAS>
__global__ __launch_bounds__(256, 4) void gemm_rt(
    const float* __restrict__ A, const float* __restrict__ W,
    const float* __restrict__ b, float* __restrict__ out, int n) {
  constexpr int JT = OUT_DIM / 4;     // threads along N (32 or 16)
  constexpr int RG = 256 / JT;        // row groups (8 or 16)
  constexpr int TILE_M = RG * MR;
  const int j  = threadIdx.x % JT;
  const int rg = threadIdx.x / JT;
  const int row0 = blockIdx.x * TILE_M + rg * MR;

  float4 bv = make_float4(0.f, 0.f, 0.f, 0.f);
  if (BIAS) bv = ((const float4*)b)[j];

  float acc[MR][4];
#pragma unroll
  for (int i = 0; i < MR; ++i) {
    acc[i][0] = bv.x; acc[i][1] = bv.y; acc[i][2] = bv.z; acc[i][3] = bv.w;
  }
  const float* Arow[MR];
#pragma unroll
  for (int i = 0; i < MR; ++i) {
    int r = row0 + i; if (r > n - 1) r = n - 1;
    Arow[i] = A + (size_t)r * DIM;
  }
  const float* Wj = W + j * 4;

  // prefetch chunk 0
  float4 cw0 = *(const float4*)(Wj + 0 * OUT_DIM);
  float4 cw1 = *(const float4*)(Wj + 1 * OUT_DIM);
  float4 cw2 = *(const float4*)(Wj + 2 * OUT_DIM);
  float4 cw3 = *(const float4*)(Wj + 3 * OUT_DIM);
  float4 ca[MR];
#pragma unroll
  for (int i = 0; i < MR; ++i) ca[i] = *(const float4*)(Arow[i]);

#pragma unroll
  for (int kk = 0; kk < DIM; kk += 4) {
    // issue next chunk's loads FIRST (in flight during the FMAs below)
    float4 nw0, nw1, nw2, nw3, na[MR];
    if (kk + 4 < DIM) {
      const float* Wn = Wj + (size_t)(kk + 4) * OUT_DIM;
      nw0 = *(const float4*)(Wn + 0 * OUT_DIM);
      nw1 = *(const float4*)(Wn + 1 * OUT_DIM);
      nw2 = *(const float4*)(Wn + 2 * OUT_DIM);
      nw3 = *(const float4*)(Wn + 3 * OUT_DIM);
#pragma unroll
      for (int i = 0; i < MR; ++i) na[i] = *(const float4*)(Arow[i] + kk + 4);
    }
    // 16*MR FMAs on current chunk
#pragma unroll
    for (int i = 0; i < MR; ++i) {
      acc[i][0] = fmaf(ca[i].x, cw0.x, acc[i][0]);
      acc[i][1] = fmaf(ca[i].x, cw0.y, acc[i][1]);
      acc[i][2] = fmaf(ca[i].x, cw0.z, acc[i][2]);
      acc[i][3] = fmaf(ca[i].x, cw0.w, acc[i][3]);
      acc[i][0] = fmaf(ca[i].y, cw1.x, acc[i][0]);
      acc[i][1] = fmaf(ca[i].y, cw1.y, acc[i][1]);
      acc[i][2] = fmaf(ca[i].y, cw1.z, acc[i][2]);
      acc[i][3] = fmaf(ca[i].y, cw1.w, acc[i][3]);
      acc[i][0] = fmaf(ca[i].z, cw2.x, acc[i][0]);
      acc[i][1] = fmaf(ca[i].z, cw2.y, acc[i][1]);
      acc[i][2] = fmaf(ca[i].z, cw2.z, acc[i][2]);
      acc[i][3] = fmaf(ca[i].z, cw2.w, acc[i][3]);
      acc[i][0] = fmaf(ca[i].w, cw3.x, acc[i][0]);
      acc[i][1] = fmaf(ca[i].w, cw3.y, acc[i][1]);
      acc[i][2] = fmaf(ca[i].w, cw3.z, acc[i][2]);
      acc[i][3] = fmaf(ca[i].w, cw3.w, acc[i][3]);
    }
    // rotate (renamed away by full unroll)
    if (kk + 4 < DIM) {
      cw0 = nw0; cw1 = nw1; cw2 = nw2; cw3 = nw3;
#pragma unroll
      for (int i = 0; i < MR; ++i) ca[i] = na[i];
    }
  }

#pragma unroll
  for (int i = 0; i < MR; ++i) {
    int row = row0 + i;
    if (NORM) {
      float v0 = fmaxf(acc[i][0], 0.f), v1 = fmaxf(acc[i][1], 0.f);
      float v2 = fmaxf(acc[i][2], 0.f), v3 = fmaxf(acc[i][3], 0.f);
      float s = v0 * v0 + v1 * v1 + v2 * v2 + v3 * v3;
#pragma unroll
      for (int off = JT / 2; off >= 1; off >>= 1) s += __shfl_xor(s, off, JT);
      float inv = 1.0f / fmaxf(sqrtf(s), 1e-12f);
      if (row < n) {
        float4 st = make_float4(v0 * inv, v1 * inv, v2 * inv, v3 * inv);
        ((float4*)(out + (size_t)row * OUT_DIM))[j] = st;
      }
    } else {
      if (row < n) {
        float4 st = make_float4(acc[i][0], acc[i][1], acc[i][2], acc[i][3]);
        ((float4*)(out + (size_t)row * OUT_DIM))[j] = st;
      }
    }
  }
}

extern "C" void kernel_launch(void* const* d_in, const int* in_sizes, int n_in,
                              void* d_out, int out_size, void* d_ws, size_t ws_size,
                              hipStream_t stream) {
  const float* x  = (const float*)d_in[0];
  const int*   ei = (const int*)d_in[1];
  const float* C  = (const float*)d_in[2];
  const float* W1 = (const float*)d_in[3];
  const float* b1 = (const float*)d_in[4];
  const float* W2 = (const float*)d_in[5];
  const float* b2 = (const float*)d_in[6];
  const float* W3 = (const float*)d_in[7];
  const float* b3 = (const float*)d_in[8];
  float* out = (float*)d_out;

  // ---- workspace layout ----
  float* prop     = (float*)d_ws;                        // NN*DIM f32 (also g[NN*64])
  float* h        = prop + (size_t)NN * DIM;             // NN*DIM f32
  int*   rowStart = (int*)(h + (size_t)NN * DIM);        // NN+1 (+pad)
  int*   cnt      = rowStart + NN + 2;                   // NN
  int*   cursor   = cnt + NN;                            // NN
  int*   bsum     = cursor + NN;                         // 256
  int*   bbase    = bsum + 256;                          // 256
  int2*  cv       = (int2*)(bbase + 256);                // NE packed (col,val)
  const size_t need = (size_t)(2 * NN * DIM) * 4 + (size_t)(3 * NN + 2 + 512) * 4 + (size_t)NE * 8;

  const dim3 blk(256);
  const int g128 = (NN + 31) / 32;   // gemm_rt<128,4> tiles 32 rows
  const int g64  = (NN + 31) / 32;   // gemm_rt<64,2>  tiles 32 rows

  if (ws_size >= need) {
    // ---- build CSR once, reuse 3x ----
    hipMemsetAsync(cnt, 0, (size_t)NN * 4, stream);
    edge_histo<<<(NE + 255) / 256, blk, 0, stream>>>(ei, cnt);
    block_sums<<<NB, blk, 0, stream>>>(cnt, bsum);
    scan_bsums<<<1, blk, 0, stream>>>(bsum, bbase);
    scan_final<<<NB, blk, 0, stream>>>(cnt, bbase, rowStart, cursor);
    edge_scatter<<<(NE + 255) / 256, blk, 0, stream>>>(ei, C, cursor, cv);

    // layer 1: prop = C@x; h = norm(relu(prop@W1 + b1))
    spmm_csr<128, false><<<(NN + 7) / 8, blk, 0, stream>>>(rowStart, cv, x, nullptr, prop);
    gemm_rt<128, 4, true, true><<<g128, blk, 0, stream>>>(prop, W1, b1, h, NN);
    // layer 2
    spmm_csr<128, false><<<(NN + 7) / 8, blk, 0, stream>>>(rowStart, cv, h, nullptr, prop);
    gemm_rt<128, 4, true, true><<<g128, blk, 0, stream>>>(prop, W2, b2, h, NN);
    // layer 3 reassociated: g = h@W3 (no bias); out = C@g + b3
    gemm_rt<64, 2, false, false><<<g64, blk, 0, stream>>>(h, W3, nullptr, prop, NN);
    spmm_csr<64, true><<<(NN + 15) / 16, blk, 0, stream>>>(rowStart, cv, prop, b3, out);
  } else {
    // fallback: atomic scatter path
    const size_t propBytes = (size_t)NN * DIM * sizeof(float);
    const int spmmGrid = 4096;
    hipMemsetAsync(prop, 0, propBytes, stream);
    spmm_atomic<<<spmmGrid, blk, 0, stream>>>(ei, C, x, prop);
    gemm_rt<128, 4, true, true><<<g128, blk, 0, stream>>>(prop, W1, b1, h, NN);
    hipMemsetAsync(prop, 0, propBytes, stream);
    spmm_atomic<<<spmmGrid, blk, 0, stream>>>(ei, C, h, prop);
    gemm_rt<128, 4, true, true><<<g128, blk, 0, stream>>>(prop, W2, b2, h, NN);
    hipMemsetAsync(prop, 0, propBytes, stream);
    spmm_atomic<<<spmmGrid, blk, 0, stream>>>(ei, C, h, prop);
    gemm_rt<64, 2, false, true><<<g64, blk, 0, stream>>>(prop, W3, b3, out, NN);
  }
}

// Round 9
// 357.897 us; speedup vs baseline: 7.9429x; 7.9429x over previous
//
#include <hip/hip_runtime.h>

#define NN 50000
#define NE 800000
#define DIM 128
#define NB ((NN + 255) / 256)   // 196 scan chunks

// ================= CSR build (edge pattern reused for all 3 layers) =================
__global__ __launch_bounds__(256) void edge_histo(const int* __restrict__ ei,
                                                  int* __restrict__ cnt) {
  int e = blockIdx.x * 256 + threadIdx.x;
  if (e >= NE) return;
  int r = ei[e], c = ei[NE + e];
  if ((unsigned)r < NN && (unsigned)c < NN) atomicAdd(&cnt[r], 1);
}

// ---- distributed 2-level exclusive scan ----
__global__ __launch_bounds__(256) void block_sums(const int* __restrict__ cnt,
                                                  int* __restrict__ bsum) {
  int i = blockIdx.x * 256 + threadIdx.x;
  int v = (i < NN) ? cnt[i] : 0;
#pragma unroll
  for (int off = 1; off < 64; off <<= 1) v += __shfl_xor(v, off, 64);
  __shared__ int ws[4];
  if ((threadIdx.x & 63) == 0) ws[threadIdx.x >> 6] = v;
  __syncthreads();
  if (threadIdx.x == 0) bsum[blockIdx.x] = ws[0] + ws[1] + ws[2] + ws[3];
}

__global__ __launch_bounds__(256) void scan_bsums(const int* __restrict__ bsum,
                                                  int* __restrict__ bbase) {
  int t = threadIdx.x;
  int v = (t < NB) ? bsum[t] : 0;
  int lane = t & 63, w = t >> 6;
  int inc = v;
#pragma unroll
  for (int off = 1; off < 64; off <<= 1) {
    int u = __shfl_up(inc, off, 64);
    if (lane >= off) inc += u;
  }
  __shared__ int ws[4];
  if (lane == 63) ws[w] = inc;
  __syncthreads();
  int wb = 0;
  for (int k = 0; k < w; ++k) wb += ws[k];
  if (t < NB) bbase[t] = wb + inc - v;
}

__global__ __launch_bounds__(256) void scan_final(const int* __restrict__ cnt,
                                                  const int* __restrict__ bbase,
                                                  int* __restrict__ rowStart,
                                                  int* __restrict__ cursor) {
  int i = blockIdx.x * 256 + threadIdx.x;
  int v = (i < NN) ? cnt[i] : 0;
  int lane = threadIdx.x & 63, w = threadIdx.x >> 6;
  int inc = v;
#pragma unroll
  for (int off = 1; off < 64; off <<= 1) {
    int u = __shfl_up(inc, off, 64);
    if (lane >= off) inc += u;
  }
  __shared__ int ws[4];
  if (lane == 63) ws[w] = inc;
  __syncthreads();
  int wb = 0;
  for (int k = 0; k < w; ++k) wb += ws[k];
  int ex = bbase[blockIdx.x] + wb + inc - v;   // global exclusive prefix
  if (i < NN) { rowStart[i] = ex; cursor[i] = ex; }
  if (i == NN - 1) rowStart[NN] = ex + v;
}

// Scatter packed (col, val) into row-sorted order.
__global__ __launch_bounds__(256) void edge_scatter(const int* __restrict__ ei,
                                                    const float* __restrict__ vals,
                                                    int* __restrict__ cursor,
                                                    int2* __restrict__ cv) {
  int e = blockIdx.x * 256 + threadIdx.x;
  if (e >= NE) return;
  int r = ei[e], c = ei[NE + e];
  if ((unsigned)r >= NN || (unsigned)c >= NN) return;
  int pos = atomicAdd(&cursor[r], 1);
  cv[pos] = make_int2(c, __float_as_int(vals[e]));
}

// ============ SpMM gather: D/4 lanes per row, regs accumulate, no atomics ============
template <int D, bool BIAS>
__global__ __launch_bounds__(256) void spmm_csr(const int* __restrict__ rowStart,
                                                const int2* __restrict__ cv,
                                                const float* __restrict__ h,
                                                const float* __restrict__ bias,
                                                float* __restrict__ out) {
  constexpr int L = D / 4;                      // lanes per row
  const int lane = threadIdx.x % L;
  const int r = blockIdx.x * (256 / L) + threadIdx.x / L;
  if (r >= NN) return;
  int p = rowStart[r], pend = rowStart[r + 1];
  float4 acc = BIAS ? ((const float4*)bias)[lane] : make_float4(0.f, 0.f, 0.f, 0.f);
  for (; p + 3 < pend; p += 4) {
    int2 e0 = cv[p], e1 = cv[p + 1], e2 = cv[p + 2], e3 = cv[p + 3];
    float4 x0 = ((const float4*)(h + (size_t)e0.x * D))[lane];
    float4 x1 = ((const float4*)(h + (size_t)e1.x * D))[lane];
    float4 x2 = ((const float4*)(h + (size_t)e2.x * D))[lane];
    float4 x3 = ((const float4*)(h + (size_t)e3.x * D))[lane];
    float v0 = __int_as_float(e0.y), v1 = __int_as_float(e1.y);
    float v2 = __int_as_float(e2.y), v3 = __int_as_float(e3.y);
    acc.x = fmaf(v0, x0.x, acc.x); acc.y = fmaf(v0, x0.y, acc.y);
    acc.z = fmaf(v0, x0.z, acc.z); acc.w = fmaf(v0, x0.w, acc.w);
    acc.x = fmaf(v1, x1.x, acc.x); acc.y = fmaf(v1, x1.y, acc.y);
    acc.z = fmaf(v1, x1.z, acc.z); acc.w = fmaf(v1, x1.w, acc.w);
    acc.x = fmaf(v2, x2.x, acc.x); acc.y = fmaf(v2, x2.y, acc.y);
    acc.z = fmaf(v2, x2.z, acc.z); acc.w = fmaf(v2, x2.w, acc.w);
    acc.x = fmaf(v3, x3.x, acc.x); acc.y = fmaf(v3, x3.y, acc.y);
    acc.z = fmaf(v3, x3.z, acc.z); acc.w = fmaf(v3, x3.w, acc.w);
  }
  for (; p < pend; ++p) {
    int2 e0 = cv[p];
    float v0 = __int_as_float(e0.y);
    float4 x0 = ((const float4*)(h + (size_t)e0.x * D))[lane];
    acc.x = fmaf(v0, x0.x, acc.x); acc.y = fmaf(v0, x0.y, acc.y);
    acc.z = fmaf(v0, x0.z, acc.z); acc.w = fmaf(v0, x0.w, acc.w);
  }
  ((float4*)(out + (size_t)r * D))[lane] = acc;
}

// ---------------- fallback: atomic scatter SpMM (if ws too small) ----------------
__global__ __launch_bounds__(256) void spmm_atomic(
    const int* __restrict__ ei, const float* __restrict__ vals,
    const float* __restrict__ h, float* __restrict__ prop) {
  const int lane32 = threadIdx.x & 31;
  int hw = blockIdx.x * (blockDim.x >> 5) + (threadIdx.x >> 5);
  const int stride = gridDim.x * (blockDim.x >> 5);
  for (int e = hw; e < NE; e += stride) {
    int r = ei[e], c = ei[NE + e];
    float v = vals[e];
    if ((unsigned)r >= NN || (unsigned)c >= NN) continue;
    float4 x = ((const float4*)(h + (size_t)c * DIM))[lane32];
    float* pp = prop + (size_t)r * DIM + lane32 * 4;
    unsafeAtomicAdd(pp + 0, v * x.x);
    unsafeAtomicAdd(pp + 1, v * x.y);
    unsafeAtomicAdd(pp + 2, v * x.z);
    unsafeAtomicAdd(pp + 3, v * x.w);
  }
}

// ========== LDS-staged dense layer: A-tile via global_load_lds, W from L2 ==========
// R8 lesson: explicit register prefetch -> scratch spill (FETCH/WRITE 1.28 GB).
// R5/R7 lesson: compiler keeps too few global loads in flight (VGPR 36, VALUBusy 23%).
// Fix: A reads become ds_read_b128 (short latency, compiler schedules these well);
// only 4 W loads/chunk remain on the global path. TILE_M=32 -> 16 KB LDS, ~6 blk/CU.
// NOTE: A must point into d_ws (staging reads overrun by <32 KB into adjacent ws).
template <int OUT_DIM, int MR, bool NORM, bool BIAS>
__global__ __launch_bounds__(256) void gemm_lds(
    const float* __restrict__ A, const float* __restrict__ W,
    const float* __restrict__ b, float* __restrict__ out, int n) {
  constexpr int JT = OUT_DIM / 4;      // threads along N (32 or 16)
  constexpr int RG = 256 / JT;         // row groups (8 or 16)
  constexpr int TILE_M = RG * MR;      // 32
  static_assert(TILE_M == 32, "staging loop assumes 32-row tile");
  __shared__ float As[TILE_M * DIM];   // 16 KB, linear

  const int tid = threadIdx.x;
  // ---- stage A[row0 .. row0+31][0..127] -> As, linear, 4 x 4KB issues ----
  const size_t gbase = (size_t)blockIdx.x * TILE_M * DIM;
#pragma unroll
  for (int it = 0; it < 4; ++it) {
    const float* g = A + gbase + it * 1024 + tid * 4;
    auto* lp = (__attribute__((address_space(3))) char*)As + it * 4096 + (tid >> 6) * 1024;
    __builtin_amdgcn_global_load_lds((const __attribute__((address_space(1))) void*)g,
                                     (__attribute__((address_space(3))) void*)lp, 16, 0, 0);
  }
  asm volatile("s_waitcnt vmcnt(0)" ::: "memory");
  __syncthreads();

  const int j  = tid % JT;
  const int rg = tid / JT;
  const int row0 = blockIdx.x * TILE_M + rg * MR;

  float4 bv = make_float4(0.f, 0.f, 0.f, 0.f);
  if (BIAS) bv = ((const float4*)b)[j];

  float acc[MR][4];
#pragma unroll
  for (int i = 0; i < MR; ++i) {
    acc[i][0] = bv.x; acc[i][1] = bv.y; acc[i][2] = bv.z; acc[i][3] = bv.w;
  }
  const float* Wj = W + j * 4;

#pragma unroll 2
  for (int kk = 0; kk < DIM; kk += 4) {
    float4 w0 = *(const float4*)(Wj + (size_t)(kk + 0) * OUT_DIM);
    float4 w1 = *(const float4*)(Wj + (size_t)(kk + 1) * OUT_DIM);
    float4 w2 = *(const float4*)(Wj + (size_t)(kk + 2) * OUT_DIM);
    float4 w3 = *(const float4*)(Wj + (size_t)(kk + 3) * OUT_DIM);
    float4 a4[MR];
#pragma unroll
    for (int i = 0; i < MR; ++i)
      a4[i] = *(const float4*)(As + (rg * MR + i) * DIM + kk);   // ds_read_b128
#pragma unroll
    for (int i = 0; i < MR; ++i) {
      acc[i][0] = fmaf(a4[i].x, w0.x, acc[i][0]);
      acc[i][1] = fmaf(a4[i].x, w0.y, acc[i][1]);
      acc[i][2] = fmaf(a4[i].x, w0.z, acc[i][2]);
      acc[i][3] = fmaf(a4[i].x, w0.w, acc[i][3]);
      acc[i][0] = fmaf(a4[i].y, w1.x, acc[i][0]);
      acc[i][1] = fmaf(a4[i].y, w1.y, acc[i][1]);
      acc[i][2] = fmaf(a4[i].y, w1.z, acc[i][2]);
      acc[i][3] = fmaf(a4[i].y, w1.w, acc[i][3]);
      acc[i][0] = fmaf(a4[i].z, w2.x, acc[i][0]);
      acc[i][1] = fmaf(a4[i].z, w2.y, acc[i][1]);
      acc[i][2] = fmaf(a4[i].z, w2.z, acc[i][2]);
      acc[i][3] = fmaf(a4[i].z, w2.w, acc[i][3]);
      acc[i][0] = fmaf(a4[i].w, w3.x, acc[i][0]);
      acc[i][1] = fmaf(a4[i].w, w3.y, acc[i][1]);
      acc[i][2] = fmaf(a4[i].w, w3.z, acc[i][2]);
      acc[i][3] = fmaf(a4[i].w, w3.w, acc[i][3]);
    }
  }

#pragma unroll
  for (int i = 0; i < MR; ++i) {
    int row = row0 + i;
    if (NORM) {
      float v0 = fmaxf(acc[i][0], 0.f), v1 = fmaxf(acc[i][1], 0.f);
      float v2 = fmaxf(acc[i][2], 0.f), v3 = fmaxf(acc[i][3], 0.f);
      float s = v0 * v0 + v1 * v1 + v2 * v2 + v3 * v3;
#pragma unroll
      for (int off = JT / 2; off >= 1; off >>= 1) s += __shfl_xor(s, off, JT);
      float inv = 1.0f / fmaxf(sqrtf(s), 1e-12f);
      if (row < n) {
        float4 st = make_float4(v0 * inv, v1 * inv, v2 * inv, v3 * inv);
        ((float4*)(out + (size_t)row * OUT_DIM))[j] = st;
      }
    } else {
      if (row < n) {
        float4 st = make_float4(acc[i][0], acc[i][1], acc[i][2], acc[i][3]);
        ((float4*)(out + (size_t)row * OUT_DIM))[j] = st;
      }
    }
  }
}

extern "C" void kernel_launch(void* const* d_in, const int* in_sizes, int n_in,
                              void* d_out, int out_size, void* d_ws, size_t ws_size,
                              hipStream_t stream) {
  const float* x  = (const float*)d_in[0];
  const int*   ei = (const int*)d_in[1];
  const float* C  = (const float*)d_in[2];
  const float* W1 = (const float*)d_in[3];
  const float* b1 = (const float*)d_in[4];
  const float* W2 = (const float*)d_in[5];
  const float* b2 = (const float*)d_in[6];
  const float* W3 = (const float*)d_in[7];
  const float* b3 = (const float*)d_in[8];
  float* out = (float*)d_out;

  // ---- workspace layout ----
  float* prop     = (float*)d_ws;                        // NN*DIM f32 (also g[NN*64])
  float* h        = prop + (size_t)NN * DIM;             // NN*DIM f32
  int*   rowStart = (int*)(h + (size_t)NN * DIM);        // NN+1 (+pad)
  int*   cnt      = rowStart + NN + 2;                   // NN
  int*   cursor   = cnt + NN;                            // NN
  int*   bsum     = cursor + NN;                         // 256
  int*   bbase    = bsum + 256;                          // 256
  int2*  cv       = (int2*)(bbase + 256);                // NE packed (col,val)
  const size_t need = (size_t)(2 * NN * DIM) * 4 + (size_t)(3 * NN + 2 + 512) * 4 + (size_t)NE * 8;

  const dim3 blk(256);
  const int gGemm = (NN + 31) / 32;   // TILE_M = 32 for both gemm_lds variants

  if (ws_size >= need) {
    // ---- build CSR once, reuse 3x ----
    hipMemsetAsync(cnt, 0, (size_t)NN * 4, stream);
    edge_histo<<<(NE + 255) / 256, blk, 0, stream>>>(ei, cnt);
    block_sums<<<NB, blk, 0, stream>>>(cnt, bsum);
    scan_bsums<<<1, blk, 0, stream>>>(bsum, bbase);
    scan_final<<<NB, blk, 0, stream>>>(cnt, bbase, rowStart, cursor);
    edge_scatter<<<(NE + 255) / 256, blk, 0, stream>>>(ei, C, cursor, cv);

    // layer 1: prop = C@x; h = norm(relu(prop@W1 + b1))   (gemm A always in ws)
    spmm_csr<128, false><<<(NN + 7) / 8, blk, 0, stream>>>(rowStart, cv, x, nullptr, prop);
    gemm_lds<128, 4, true, true><<<gGemm, blk, 0, stream>>>(prop, W1, b1, h, NN);
    // layer 2
    spmm_csr<128, false><<<(NN + 7) / 8, blk, 0, stream>>>(rowStart, cv, h, nullptr, prop);
    gemm_lds<128, 4, true, true><<<gGemm, blk, 0, stream>>>(prop, W2, b2, h, NN);
    // layer 3 reassociated: g = h@W3 (no bias); out = C@g + b3
    gemm_lds<64, 2, false, false><<<gGemm, blk, 0, stream>>>(h, W3, nullptr, prop, NN);
    spmm_csr<64, true><<<(NN + 15) / 16, blk, 0, stream>>>(rowStart, cv, prop, b3, out);
  } else {
    // fallback: atomic scatter path (gemm A still in ws)
    const size_t propBytes = (size_t)NN * DIM * sizeof(float);
    const int spmmGrid = 4096;
    hipMemsetAsync(prop, 0, propBytes, stream);
    spmm_atomic<<<spmmGrid, blk, 0, stream>>>(ei, C, x, prop);
    gemm_lds<128, 4, true, true><<<gGemm, blk, 0, stream>>>(prop, W1, b1, h, NN);
    hipMemsetAsync(prop, 0, propBytes, stream);
    spmm_atomic<<<spmmGrid, blk, 0, stream>>>(ei, C, h, prop);
    gemm_lds<128, 4, true, true><<<gGemm, blk, 0, stream>>>(prop, W2, b2, h, NN);
    hipMemsetAsync(prop, 0, propBytes, stream);
    spmm_atomic<<<spmmGrid, blk, 0, stream>>>(ei, C, h, prop);
    gemm_lds<64, 2, false, true><<<gGemm, blk, 0, stream>>>(prop, W3, b3, out, NN);
  }
}

// Round 10
// 312.708 us; speedup vs baseline: 9.0907x; 1.1445x over previous
//
#include <hip/hip_runtime.h>

#define NN 50000
#define NE 800000
#define DIM 128
#define NB ((NN + 255) / 256)   // 196 scan chunks

// ================= CSR build (edge pattern reused for all 3 layers) =================
// Histogram + per-edge position in one pass: pos[e] = rank of edge e within its row.
__global__ __launch_bounds__(256) void edge_histo_pos(const int* __restrict__ ei,
                                                      int* __restrict__ cnt,
                                                      int* __restrict__ pos) {
  int e = blockIdx.x * 256 + threadIdx.x;
  if (e >= NE) return;
  int r = ei[e], c = ei[NE + e];
  int p = -1;
  if ((unsigned)r < NN && (unsigned)c < NN) p = atomicAdd(&cnt[r], 1);
  pos[e] = p;   // coalesced
}

// ---- distributed 2-level exclusive scan ----
__global__ __launch_bounds__(256) void block_sums(const int* __restrict__ cnt,
                                                  int* __restrict__ bsum) {
  int i = blockIdx.x * 256 + threadIdx.x;
  int v = (i < NN) ? cnt[i] : 0;
#pragma unroll
  for (int off = 1; off < 64; off <<= 1) v += __shfl_xor(v, off, 64);
  __shared__ int ws[4];
  if ((threadIdx.x & 63) == 0) ws[threadIdx.x >> 6] = v;
  __syncthreads();
  if (threadIdx.x == 0) bsum[blockIdx.x] = ws[0] + ws[1] + ws[2] + ws[3];
}

__global__ __launch_bounds__(256) void scan_bsums(const int* __restrict__ bsum,
                                                  int* __restrict__ bbase) {
  int t = threadIdx.x;
  int v = (t < NB) ? bsum[t] : 0;
  int lane = t & 63, w = t >> 6;
  int inc = v;
#pragma unroll
  for (int off = 1; off < 64; off <<= 1) {
    int u = __shfl_up(inc, off, 64);
    if (lane >= off) inc += u;
  }
  __shared__ int ws[4];
  if (lane == 63) ws[w] = inc;
  __syncthreads();
  int wb = 0;
  for (int k = 0; k < w; ++k) wb += ws[k];
  if (t < NB) bbase[t] = wb + inc - v;
}

__global__ __launch_bounds__(256) void scan_final(const int* __restrict__ cnt,
                                                  const int* __restrict__ bbase,
                                                  int* __restrict__ rowStart) {
  int i = blockIdx.x * 256 + threadIdx.x;
  int v = (i < NN) ? cnt[i] : 0;
  int lane = threadIdx.x & 63, w = threadIdx.x >> 6;
  int inc = v;
#pragma unroll
  for (int off = 1; off < 64; off <<= 1) {
    int u = __shfl_up(inc, off, 64);
    if (lane >= off) inc += u;
  }
  __shared__ int ws[4];
  if (lane == 63) ws[w] = inc;
  __syncthreads();
  int wb = 0;
  for (int k = 0; k < w; ++k) wb += ws[k];
  int ex = bbase[blockIdx.x] + wb + inc - v;   // global exclusive prefix
  if (i < NN) rowStart[i] = ex;
  if (i == NN - 1) rowStart[NN] = ex + v;
}

// Atomic-free scatter: position precomputed, pure address math + scattered write.
__global__ __launch_bounds__(256) void edge_scatter(const int* __restrict__ ei,
                                                    const float* __restrict__ vals,
                                                    const int* __restrict__ rowStart,
                                                    const int* __restrict__ pos,
                                                    int2* __restrict__ cv) {
  int e = blockIdx.x * 256 + threadIdx.x;
  if (e >= NE) return;
  int p = pos[e];
  if (p < 0) return;
  int r = ei[e], c = ei[NE + e];
  cv[rowStart[r] + p] = make_int2(c, __float_as_int(vals[e]));
}

// ============ SpMM gather: D/4 lanes per row, regs accumulate, no atomics ============
template <int D, bool BIAS>
__global__ __launch_bounds__(256) void spmm_csr(const int* __restrict__ rowStart,
                                                const int2* __restrict__ cv,
                                                const float* __restrict__ h,
                                                const float* __restrict__ bias,
                                                float* __restrict__ out) {
  constexpr int L = D / 4;                      // lanes per row
  const int lane = threadIdx.x % L;
  const int r = blockIdx.x * (256 / L) + threadIdx.x / L;
  if (r >= NN) return;
  int p = rowStart[r], pend = rowStart[r + 1];
  float4 acc = BIAS ? ((const float4*)bias)[lane] : make_float4(0.f, 0.f, 0.f, 0.f);
  for (; p + 3 < pend; p += 4) {
    int2 e0 = cv[p], e1 = cv[p + 1], e2 = cv[p + 2], e3 = cv[p + 3];
    float4 x0 = ((const float4*)(h + (size_t)e0.x * D))[lane];
    float4 x1 = ((const float4*)(h + (size_t)e1.x * D))[lane];
    float4 x2 = ((const float4*)(h + (size_t)e2.x * D))[lane];
    float4 x3 = ((const float4*)(h + (size_t)e3.x * D))[lane];
    float v0 = __int_as_float(e0.y), v1 = __int_as_float(e1.y);
    float v2 = __int_as_float(e2.y), v3 = __int_as_float(e3.y);
    acc.x = fmaf(v0, x0.x, acc.x); acc.y = fmaf(v0, x0.y, acc.y);
    acc.z = fmaf(v0, x0.z, acc.z); acc.w = fmaf(v0, x0.w, acc.w);
    acc.x = fmaf(v1, x1.x, acc.x); acc.y = fmaf(v1, x1.y, acc.y);
    acc.z = fmaf(v1, x1.z, acc.z); acc.w = fmaf(v1, x1.w, acc.w);
    acc.x = fmaf(v2, x2.x, acc.x); acc.y = fmaf(v2, x2.y, acc.y);
    acc.z = fmaf(v2, x2.z, acc.z); acc.w = fmaf(v2, x2.w, acc.w);
    acc.x = fmaf(v3, x3.x, acc.x); acc.y = fmaf(v3, x3.y, acc.y);
    acc.z = fmaf(v3, x3.z, acc.z); acc.w = fmaf(v3, x3.w, acc.w);
  }
  for (; p < pend; ++p) {
    int2 e0 = cv[p];
    float v0 = __int_as_float(e0.y);
    float4 x0 = ((const float4*)(h + (size_t)e0.x * D))[lane];
    acc.x = fmaf(v0, x0.x, acc.x); acc.y = fmaf(v0, x0.y, acc.y);
    acc.z = fmaf(v0, x0.z, acc.z); acc.w = fmaf(v0, x0.w, acc.w);
  }
  ((float4*)(out + (size_t)r * D))[lane] = acc;
}

// ---------------- fallback: atomic scatter SpMM (if ws too small) ----------------
__global__ __launch_bounds__(256) void spmm_atomic(
    const int* __restrict__ ei, const float* __restrict__ vals,
    const float* __restrict__ h, float* __restrict__ prop) {
  const int lane32 = threadIdx.x & 31;
  int hw = blockIdx.x * (blockDim.x >> 5) + (threadIdx.x >> 5);
  const int stride = gridDim.x * (blockDim.x >> 5);
  for (int e = hw; e < NE; e += stride) {
    int r = ei[e], c = ei[NE + e];
    float v = vals[e];
    if ((unsigned)r >= NN || (unsigned)c >= NN) continue;
    float4 x = ((const float4*)(h + (size_t)c * DIM))[lane32];
    float* pp = prop + (size_t)r * DIM + lane32 * 4;
    unsafeAtomicAdd(pp + 0, v * x.x);
    unsafeAtomicAdd(pp + 1, v * x.y);
    unsafeAtomicAdd(pp + 2, v * x.z);
    unsafeAtomicAdd(pp + 3, v * x.w);
  }
}

// ========== LDS-staged dense layer: A-tile via global_load_lds, W from L2 ==========
// A reads are ds_read_b128; only 4 W loads/chunk on the global path (L2-hot).
// TILE_M=32 -> 16 KB LDS. A must point into d_ws (staging may overrun < 32 KB).
template <int OUT_DIM, int MR, bool NORM, bool BIAS>
__global__ __launch_bounds__(256) void gemm_lds(
    const float* __restrict__ A, const float* __restrict__ W,
    const float* __restrict__ b, float* __restrict__ out, int n) {
  constexpr int JT = OUT_DIM / 4;      // threads along N (32 or 16)
  constexpr int RG = 256 / JT;         // row groups (8 or 16)
  constexpr int TILE_M = RG * MR;      // 32
  static_assert(TILE_M == 32, "staging loop assumes 32-row tile");
  __shared__ float As[TILE_M * DIM];   // 16 KB, linear

  const int tid = threadIdx.x;
  const size_t gbase = (size_t)blockIdx.x * TILE_M * DIM;
#pragma unroll
  for (int it = 0; it < 4; ++it) {
    const float* g = A + gbase + it * 1024 + tid * 4;
    auto* lp = (__attribute__((address_space(3))) char*)As + it * 4096 + (tid >> 6) * 1024;
    __builtin_amdgcn_global_load_lds((const __attribute__((address_space(1))) void*)g,
                                     (__attribute__((address_space(3))) void*)lp, 16, 0, 0);
  }
  asm volatile("s_waitcnt vmcnt(0)" ::: "memory");
  __syncthreads();

  const int j  = tid % JT;
  const int rg = tid / JT;
  const int row0 = blockIdx.x * TILE_M + rg * MR;

  float4 bv = make_float4(0.f, 0.f, 0.f, 0.f);
  if (BIAS) bv = ((const float4*)b)[j];

  float acc[MR][4];
#pragma unroll
  for (int i = 0; i < MR; ++i) {
    acc[i][0] = bv.x; acc[i][1] = bv.y; acc[i][2] = bv.z; acc[i][3] = bv.w;
  }
  const float* Wj = W + j * 4;

#pragma unroll 2
  for (int kk = 0; kk < DIM; kk += 4) {
    float4 w0 = *(const float4*)(Wj + (size_t)(kk + 0) * OUT_DIM);
    float4 w1 = *(const float4*)(Wj + (size_t)(kk + 1) * OUT_DIM);
    float4 w2 = *(const float4*)(Wj + (size_t)(kk + 2) * OUT_DIM);
    float4 w3 = *(const float4*)(Wj + (size_t)(kk + 3) * OUT_DIM);
    float4 a4[MR];
#pragma unroll
    for (int i = 0; i < MR; ++i)
      a4[i] = *(const float4*)(As + (rg * MR + i) * DIM + kk);   // ds_read_b128
#pragma unroll
    for (int i = 0; i < MR; ++i) {
      acc[i][0] = fmaf(a4[i].x, w0.x, acc[i][0]);
      acc[i][1] = fmaf(a4[i].x, w0.y, acc[i][1]);
      acc[i][2] = fmaf(a4[i].x, w0.z, acc[i][2]);
      acc[i][3] = fmaf(a4[i].x, w0.w, acc[i][3]);
      acc[i][0] = fmaf(a4[i].y, w1.x, acc[i][0]);
      acc[i][1] = fmaf(a4[i].y, w1.y, acc[i][1]);
      acc[i][2] = fmaf(a4[i].y, w1.z, acc[i][2]);
      acc[i][3] = fmaf(a4[i].y, w1.w, acc[i][3]);
      acc[i][0] = fmaf(a4[i].z, w2.x, acc[i][0]);
      acc[i][1] = fmaf(a4[i].z, w2.y, acc[i][1]);
      acc[i][2] = fmaf(a4[i].z, w2.z, acc[i][2]);
      acc[i][3] = fmaf(a4[i].z, w2.w, acc[i][3]);
      acc[i][0] = fmaf(a4[i].w, w3.x, acc[i][0]);
      acc[i][1] = fmaf(a4[i].w, w3.y, acc[i][1]);
      acc[i][2] = fmaf(a4[i].w, w3.z, acc[i][2]);
      acc[i][3] = fmaf(a4[i].w, w3.w, acc[i][3]);
    }
  }

#pragma unroll
  for (int i = 0; i < MR; ++i) {
    int row = row0 + i;
    if (NORM) {
      float v0 = fmaxf(acc[i][0], 0.f), v1 = fmaxf(acc[i][1], 0.f);
      float v2 = fmaxf(acc[i][2], 0.f), v3 = fmaxf(acc[i][3], 0.f);
      float s = v0 * v0 + v1 * v1 + v2 * v2 + v3 * v3;
#pragma unroll
      for (int off = JT / 2; off >= 1; off >>= 1) s += __shfl_xor(s, off, JT);
      float inv = 1.0f / fmaxf(sqrtf(s), 1e-12f);
      if (row < n) {
        float4 st = make_float4(v0 * inv, v1 * inv, v2 * inv, v3 * inv);
        ((float4*)(out + (size_t)row * OUT_DIM))[j] = st;
      }
    } else {
      if (row < n) {
        float4 st = make_float4(acc[i][0], acc[i][1], acc[i][2], acc[i][3]);
        ((float4*)(out + (size_t)row * OUT_DIM))[j] = st;
      }
    }
  }
}

extern "C" void kernel_launch(void* const* d_in, const int* in_sizes, int n_in,
                              void* d_out, int out_size, void* d_ws, size_t ws_size,
                              hipStream_t stream) {
  const float* x  = (const float*)d_in[0];
  const int*   ei = (const int*)d_in[1];
  const float* C  = (const float*)d_in[2];
  const float* W1 = (const float*)d_in[3];
  const float* b1 = (const float*)d_in[4];
  const float* W2 = (const float*)d_in[5];
  const float* b2 = (const float*)d_in[6];
  const float* W3 = (const float*)d_in[7];
  const float* b3 = (const float*)d_in[8];
  float* out = (float*)d_out;

  // ---- workspace layout ----
  float* prop     = (float*)d_ws;                        // NN*DIM f32 (also g[NN*64])
  float* h        = prop + (size_t)NN * DIM;             // NN*DIM f32
  int*   rowStart = (int*)(h + (size_t)NN * DIM);        // NN+1 (+pad)
  int*   cnt      = rowStart + NN + 2;                   // NN
  int*   bsum     = cnt + NN;                            // 256
  int*   bbase    = bsum + 256;                          // 256
  int*   pos      = bbase + 256;                         // NE per-edge rank
  int2*  cv       = (int2*)(pos + NE);                   // NE packed (col,val)
  const size_t need = (size_t)(2 * NN * DIM) * 4 + (size_t)(2 * NN + 2 + 512) * 4 +
                      (size_t)NE * 4 + (size_t)NE * 8;

  const dim3 blk(256);
  const int gGemm = (NN + 31) / 32;   // TILE_M = 32 for both gemm_lds variants
  const int gEdge = (NE + 255) / 256;

  if (ws_size >= need) {
    // ---- build CSR once, reuse 3x ----
    hipMemsetAsync(cnt, 0, (size_t)NN * 4, stream);
    edge_histo_pos<<<gEdge, blk, 0, stream>>>(ei, cnt, pos);
    block_sums<<<NB, blk, 0, stream>>>(cnt, bsum);
    scan_bsums<<<1, blk, 0, stream>>>(bsum, bbase);
    scan_final<<<NB, blk, 0, stream>>>(cnt, bbase, rowStart);
    edge_scatter<<<gEdge, blk, 0, stream>>>(ei, C, rowStart, pos, cv);

    // layer 1: prop = C@x; h = norm(relu(prop@W1 + b1))   (gemm A always in ws)
    spmm_csr<128, false><<<(NN + 7) / 8, blk, 0, stream>>>(rowStart, cv, x, nullptr, prop);
    gemm_lds<128, 4, true, true><<<gGemm, blk, 0, stream>>>(prop, W1, b1, h, NN);
    // layer 2
    spmm_csr<128, false><<<(NN + 7) / 8, blk, 0, stream>>>(rowStart, cv, h, nullptr, prop);
    gemm_lds<128, 4, true, true><<<gGemm, blk, 0, stream>>>(prop, W2, b2, h, NN);
    // layer 3 reassociated: g = h@W3 (no bias); out = C@g + b3
    gemm_lds<64, 2, false, false><<<gGemm, blk, 0, stream>>>(h, W3, nullptr, prop, NN);
    spmm_csr<64, true><<<(NN + 15) / 16, blk, 0, stream>>>(rowStart, cv, prop, b3, out);
  } else {
    // fallback: atomic scatter path (gemm A still in ws)
    const size_t propBytes = (size_t)NN * DIM * sizeof(float);
    const int spmmGrid = 4096;
    hipMemsetAsync(prop, 0, propBytes, stream);
    spmm_atomic<<<spmmGrid, blk, 0, stream>>>(ei, C, x, prop);
    gemm_lds<128, 4, true, true><<<gGemm, blk, 0, stream>>>(prop, W1, b1, h, NN);
    hipMemsetAsync(prop, 0, propBytes, stream);
    spmm_atomic<<<spmmGrid, blk, 0, stream>>>(ei, C, h, prop);
    gemm_lds<128, 4, true, true><<<gGemm, blk, 0, stream>>>(prop, W2, b2, h, NN);
    hipMemsetAsync(prop, 0, propBytes, stream);
    spmm_atomic<<<spmmGrid, blk, 0, stream>>>(ei, C, h, prop);
    gemm_lds<64, 2, false, true><<<gGemm, blk, 0, stream>>>(prop, W3, b3, out, NN);
  }
}

// Round 12
// 311.339 us; speedup vs baseline: 9.1307x; 1.0044x over previous
//
#include <hip/hip_runtime.h>

#define NN 50000
#define NE 800000
#define DIM 128
#define NB ((NN + 255) / 256)   // 196 scan chunks

// ================= CSR build (edge pattern reused for all 3 layers) =================
// Histogram + per-edge position in one pass: pos[e] = rank of edge e within its row.
__global__ __launch_bounds__(256) void edge_histo_pos(const int* __restrict__ ei,
                                                      int* __restrict__ cnt,
                                                      int* __restrict__ pos) {
  int e = blockIdx.x * 256 + threadIdx.x;
  if (e >= NE) return;
  int r = ei[e], c = ei[NE + e];
  int p = -1;
  if ((unsigned)r < NN && (unsigned)c < NN) p = atomicAdd(&cnt[r], 1);
  pos[e] = p;   // coalesced
}

// ---- distributed 2-level exclusive scan ----
__global__ __launch_bounds__(256) void block_sums(const int* __restrict__ cnt,
                                                  int* __restrict__ bsum) {
  int i = blockIdx.x * 256 + threadIdx.x;
  int v = (i < NN) ? cnt[i] : 0;
#pragma unroll
  for (int off = 1; off < 64; off <<= 1) v += __shfl_xor(v, off, 64);
  __shared__ int ws[4];
  if ((threadIdx.x & 63) == 0) ws[threadIdx.x >> 6] = v;
  __syncthreads();
  if (threadIdx.x == 0) bsum[blockIdx.x] = ws[0] + ws[1] + ws[2] + ws[3];
}

__global__ __launch_bounds__(256) void scan_bsums(const int* __restrict__ bsum,
                                                  int* __restrict__ bbase) {
  int t = threadIdx.x;
  int v = (t < NB) ? bsum[t] : 0;
  int lane = t & 63, w = t >> 6;
  int inc = v;
#pragma unroll
  for (int off = 1; off < 64; off <<= 1) {
    int u = __shfl_up(inc, off, 64);
    if (lane >= off) inc += u;
  }
  __shared__ int ws[4];
  if (lane == 63) ws[w] = inc;
  __syncthreads();
  int wb = 0;
  for (int k = 0; k < w; ++k) wb += ws[k];
  if (t < NB) bbase[t] = wb + inc - v;
}

__global__ __launch_bounds__(256) void scan_final(const int* __restrict__ cnt,
                                                  const int* __restrict__ bbase,
                                                  int* __restrict__ rowStart) {
  int i = blockIdx.x * 256 + threadIdx.x;
  int v = (i < NN) ? cnt[i] : 0;
  int lane = threadIdx.x & 63, w = threadIdx.x >> 6;
  int inc = v;
#pragma unroll
  for (int off = 1; off < 64; off <<= 1) {
    int u = __shfl_up(inc, off, 64);
    if (lane >= off) inc += u;
  }
  __shared__ int ws[4];
  if (lane == 63) ws[w] = inc;
  __syncthreads();
  int wb = 0;
  for (int k = 0; k < w; ++k) wb += ws[k];
  int ex = bbase[blockIdx.x] + wb + inc - v;   // global exclusive prefix
  if (i < NN) rowStart[i] = ex;
  if (i == NN - 1) rowStart[NN] = ex + v;
}

// Atomic-free scatter: position precomputed, pure address math + scattered write.
__global__ __launch_bounds__(256) void edge_scatter(const int* __restrict__ ei,
                                                    const float* __restrict__ vals,
                                                    const int* __restrict__ rowStart,
                                                    const int* __restrict__ pos,
                                                    int2* __restrict__ cv) {
  int e = blockIdx.x * 256 + threadIdx.x;
  if (e >= NE) return;
  int p = pos[e];
  if (p < 0) return;
  int r = ei[e], c = ei[NE + e];
  cv[rowStart[r] + p] = make_int2(c, __float_as_int(vals[e]));
}

// ============ SpMM gather: D/4 lanes per row, regs accumulate, no atomics ============
// R10 counters: VGPR=24 (= exactly the unroll-4 window), VALUBusy 12.5% -> latency-bound
// hypothesis. Unroll-8: 8 gathers + 8 edge loads in flight (~56 VGPR, still 8 w/SIMD).
// (R11: FMA4 macro broke on token capture of ".x"; inline function instead.)
__device__ __forceinline__ void fma4(float v, const float4& x, float4& acc) {
  acc.x = fmaf(v, x.x, acc.x);
  acc.y = fmaf(v, x.y, acc.y);
  acc.z = fmaf(v, x.z, acc.z);
  acc.w = fmaf(v, x.w, acc.w);
}

template <int D, bool BIAS>
__global__ __launch_bounds__(256) void spmm_csr(const int* __restrict__ rowStart,
                                                const int2* __restrict__ cv,
                                                const float* __restrict__ h,
                                                const float* __restrict__ bias,
                                                float* __restrict__ out) {
  constexpr int L = D / 4;                      // lanes per row
  const int lane = threadIdx.x % L;
  const int r = blockIdx.x * (256 / L) + threadIdx.x / L;
  if (r >= NN) return;
  int p = rowStart[r], pend = rowStart[r + 1];
  float4 acc = BIAS ? ((const float4*)bias)[lane] : make_float4(0.f, 0.f, 0.f, 0.f);
  for (; p + 7 < pend; p += 8) {
    int2 e0 = cv[p],     e1 = cv[p + 1], e2 = cv[p + 2], e3 = cv[p + 3];
    int2 e4 = cv[p + 4], e5 = cv[p + 5], e6 = cv[p + 6], e7 = cv[p + 7];
    float4 x0 = ((const float4*)(h + (size_t)e0.x * D))[lane];
    float4 x1 = ((const float4*)(h + (size_t)e1.x * D))[lane];
    float4 x2 = ((const float4*)(h + (size_t)e2.x * D))[lane];
    float4 x3 = ((const float4*)(h + (size_t)e3.x * D))[lane];
    float4 x4 = ((const float4*)(h + (size_t)e4.x * D))[lane];
    float4 x5 = ((const float4*)(h + (size_t)e5.x * D))[lane];
    float4 x6 = ((const float4*)(h + (size_t)e6.x * D))[lane];
    float4 x7 = ((const float4*)(h + (size_t)e7.x * D))[lane];
    fma4(__int_as_float(e0.y), x0, acc);
    fma4(__int_as_float(e1.y), x1, acc);
    fma4(__int_as_float(e2.y), x2, acc);
    fma4(__int_as_float(e3.y), x3, acc);
    fma4(__int_as_float(e4.y), x4, acc);
    fma4(__int_as_float(e5.y), x5, acc);
    fma4(__int_as_float(e6.y), x6, acc);
    fma4(__int_as_float(e7.y), x7, acc);
  }
  for (; p + 3 < pend; p += 4) {
    int2 e0 = cv[p], e1 = cv[p + 1], e2 = cv[p + 2], e3 = cv[p + 3];
    float4 x0 = ((const float4*)(h + (size_t)e0.x * D))[lane];
    float4 x1 = ((const float4*)(h + (size_t)e1.x * D))[lane];
    float4 x2 = ((const float4*)(h + (size_t)e2.x * D))[lane];
    float4 x3 = ((const float4*)(h + (size_t)e3.x * D))[lane];
    fma4(__int_as_float(e0.y), x0, acc);
    fma4(__int_as_float(e1.y), x1, acc);
    fma4(__int_as_float(e2.y), x2, acc);
    fma4(__int_as_float(e3.y), x3, acc);
  }
  for (; p < pend; ++p) {
    int2 e0 = cv[p];
    float4 x0 = ((const float4*)(h + (size_t)e0.x * D))[lane];
    fma4(__int_as_float(e0.y), x0, acc);
  }
  ((float4*)(out + (size_t)r * D))[lane] = acc;
}

// ---------------- fallback: atomic scatter SpMM (if ws too small) ----------------
__global__ __launch_bounds__(256) void spmm_atomic(
    const int* __restrict__ ei, const float* __restrict__ vals,
    const float* __restrict__ h, float* __restrict__ prop) {
  const int lane32 = threadIdx.x & 31;
  int hw = blockIdx.x * (blockDim.x >> 5) + (threadIdx.x >> 5);
  const int stride = gridDim.x * (blockDim.x >> 5);
  for (int e = hw; e < NE; e += stride) {
    int r = ei[e], c = ei[NE + e];
    float v = vals[e];
    if ((unsigned)r >= NN || (unsigned)c >= NN) continue;
    float4 x = ((const float4*)(h + (size_t)c * DIM))[lane32];
    float* pp = prop + (size_t)r * DIM + lane32 * 4;
    unsafeAtomicAdd(pp + 0, v * x.x);
    unsafeAtomicAdd(pp + 1, v * x.y);
    unsafeAtomicAdd(pp + 2, v * x.z);
    unsafeAtomicAdd(pp + 3, v * x.w);
  }
}

// ========== LDS-staged dense layer: A-tile via global_load_lds, W from L2 ==========
// A reads are ds_read_b128; only 4 W loads/chunk on the global path (L2-hot).
// TILE_M=32 -> 16 KB LDS. A must point into d_ws (staging may overrun < 32 KB).
template <int OUT_DIM, int MR, bool NORM, bool BIAS>
__global__ __launch_bounds__(256) void gemm_lds(
    const float* __restrict__ A, const float* __restrict__ W,
    const float* __restrict__ b, float* __restrict__ out, int n) {
  constexpr int JT = OUT_DIM / 4;      // threads along N (32 or 16)
  constexpr int RG = 256 / JT;         // row groups (8 or 16)
  constexpr int TILE_M = RG * MR;      // 32
  static_assert(TILE_M == 32, "staging loop assumes 32-row tile");
  __shared__ float As[TILE_M * DIM];   // 16 KB, linear

  const int tid = threadIdx.x;
  const size_t gbase = (size_t)blockIdx.x * TILE_M * DIM;
#pragma unroll
  for (int it = 0; it < 4; ++it) {
    const float* g = A + gbase + it * 1024 + tid * 4;
    auto* lp = (__attribute__((address_space(3))) char*)As + it * 4096 + (tid >> 6) * 1024;
    __builtin_amdgcn_global_load_lds((const __attribute__((address_space(1))) void*)g,
                                     (__attribute__((address_space(3))) void*)lp, 16, 0, 0);
  }
  asm volatile("s_waitcnt vmcnt(0)" ::: "memory");
  __syncthreads();

  const int j  = tid % JT;
  const int rg = tid / JT;
  const int row0 = blockIdx.x * TILE_M + rg * MR;

  float4 bv = make_float4(0.f, 0.f, 0.f, 0.f);
  if (BIAS) bv = ((const float4*)b)[j];

  float acc[MR][4];
#pragma unroll
  for (int i = 0; i < MR; ++i) {
    acc[i][0] = bv.x; acc[i][1] = bv.y; acc[i][2] = bv.z; acc[i][3] = bv.w;
  }
  const float* Wj = W + j * 4;

#pragma unroll 2
  for (int kk = 0; kk < DIM; kk += 4) {
    float4 w0 = *(const float4*)(Wj + (size_t)(kk + 0) * OUT_DIM);
    float4 w1 = *(const float4*)(Wj + (size_t)(kk + 1) * OUT_DIM);
    float4 w2 = *(const float4*)(Wj + (size_t)(kk + 2) * OUT_DIM);
    float4 w3 = *(const float4*)(Wj + (size_t)(kk + 3) * OUT_DIM);
    float4 a4[MR];
#pragma unroll
    for (int i = 0; i < MR; ++i)
      a4[i] = *(const float4*)(As + (rg * MR + i) * DIM + kk);   // ds_read_b128
#pragma unroll
    for (int i = 0; i < MR; ++i) {
      acc[i][0] = fmaf(a4[i].x, w0.x, acc[i][0]);
      acc[i][1] = fmaf(a4[i].x, w0.y, acc[i][1]);
      acc[i][2] = fmaf(a4[i].x, w0.z, acc[i][2]);
      acc[i][3] = fmaf(a4[i].x, w0.w, acc[i][3]);
      acc[i][0] = fmaf(a4[i].y, w1.x, acc[i][0]);
      acc[i][1] = fmaf(a4[i].y, w1.y, acc[i][1]);
      acc[i][2] = fmaf(a4[i].y, w1.z, acc[i][2]);
      acc[i][3] = fmaf(a4[i].y, w1.w, acc[i][3]);
      acc[i][0] = fmaf(a4[i].z, w2.x, acc[i][0]);
      acc[i][1] = fmaf(a4[i].z, w2.y, acc[i][1]);
      acc[i][2] = fmaf(a4[i].z, w2.z, acc[i][2]);
      acc[i][3] = fmaf(a4[i].z, w2.w, acc[i][3]);
      acc[i][0] = fmaf(a4[i].w, w3.x, acc[i][0]);
      acc[i][1] = fmaf(a4[i].w, w3.y, acc[i][1]);
      acc[i][2] = fmaf(a4[i].w, w3.z, acc[i][2]);
      acc[i][3] = fmaf(a4[i].w, w3.w, acc[i][3]);
    }
  }

#pragma unroll
  for (int i = 0; i < MR; ++i) {
    int row = row0 + i;
    if (NORM) {
      float v0 = fmaxf(acc[i][0], 0.f), v1 = fmaxf(acc[i][1], 0.f);
      float v2 = fmaxf(acc[i][2], 0.f), v3 = fmaxf(acc[i][3], 0.f);
      float s = v0 * v0 + v1 * v1 + v2 * v2 + v3 * v3;
#pragma unroll
      for (int off = JT / 2; off >= 1; off >>= 1) s += __shfl_xor(s, off, JT);
      float inv = 1.0f / fmaxf(sqrtf(s), 1e-12f);
      if (row < n) {
        float4 st = make_float4(v0 * inv, v1 * inv, v2 * inv, v3 * inv);
        ((float4*)(out + (size_t)row * OUT_DIM))[j] = st;
      }
    } else {
      if (row < n) {
        float4 st = make_float4(acc[i][0], acc[i][1], acc[i][2], acc[i][3]);
        ((float4*)(out + (size_t)row * OUT_DIM))[j] = st;
      }
    }
  }
}

extern "C" void kernel_launch(void* const* d_in, const int* in_sizes, int n_in,
                              void* d_out, int out_size, void* d_ws, size_t ws_size,
                              hipStream_t stream) {
  const float* x  = (const float*)d_in[0];
  const int*   ei = (const int*)d_in[1];
  const float* C  = (const float*)d_in[2];
  const float* W1 = (const float*)d_in[3];
  const float* b1 = (const float*)d_in[4];
  const float* W2 = (const float*)d_in[5];
  const float* b2 = (const float*)d_in[6];
  const float* W3 = (const float*)d_in[7];
  const float* b3 = (const float*)d_in[8];
  float* out = (float*)d_out;

  // ---- workspace layout ----
  float* prop     = (float*)d_ws;                        // NN*DIM f32 (also g[NN*64])
  float* h        = prop + (size_t)NN * DIM;             // NN*DIM f32
  int*   rowStart = (int*)(h + (size_t)NN * DIM);        // NN+1 (+pad)
  int*   cnt      = rowStart + NN + 2;                   // NN
  int*   bsum     = cnt + NN;                            // 256
  int*   bbase    = bsum + 256;                          // 256
  int*   pos      = bbase + 256;                         // NE per-edge rank
  int2*  cv       = (int2*)(pos + NE);                   // NE packed (col,val)
  const size_t need = (size_t)(2 * NN * DIM) * 4 + (size_t)(2 * NN + 2 + 512) * 4 +
                      (size_t)NE * 4 + (size_t)NE * 8;

  const dim3 blk(256);
  const int gGemm = (NN + 31) / 32;   // TILE_M = 32 for both gemm_lds variants
  const int gEdge = (NE + 255) / 256;

  if (ws_size >= need) {
    // ---- build CSR once, reuse 3x ----
    hipMemsetAsync(cnt, 0, (size_t)NN * 4, stream);
    edge_histo_pos<<<gEdge, blk, 0, stream>>>(ei, cnt, pos);
    block_sums<<<NB, blk, 0, stream>>>(cnt, bsum);
    scan_bsums<<<1, blk, 0, stream>>>(bsum, bbase);
    scan_final<<<NB, blk, 0, stream>>>(cnt, bbase, rowStart);
    edge_scatter<<<gEdge, blk, 0, stream>>>(ei, C, rowStart, pos, cv);

    // layer 1: prop = C@x; h = norm(relu(prop@W1 + b1))   (gemm A always in ws)
    spmm_csr<128, false><<<(NN + 7) / 8, blk, 0, stream>>>(rowStart, cv, x, nullptr, prop);
    gemm_lds<128, 4, true, true><<<gGemm, blk, 0, stream>>>(prop, W1, b1, h, NN);
    // layer 2
    spmm_csr<128, false><<<(NN + 7) / 8, blk, 0, stream>>>(rowStart, cv, h, nullptr, prop);
    gemm_lds<128, 4, true, true><<<gGemm, blk, 0, stream>>>(prop, W2, b2, h, NN);
    // layer 3 reassociated: g = h@W3 (no bias); out = C@g + b3
    gemm_lds<64, 2, false, false><<<gGemm, blk, 0, stream>>>(h, W3, nullptr, prop, NN);
    spmm_csr<64, true><<<(NN + 15) / 16, blk, 0, stream>>>(rowStart, cv, prop, b3, out);
  } else {
    // fallback: atomic scatter path (gemm A still in ws)
    const size_t propBytes = (size_t)NN * DIM * sizeof(float);
    const int spmmGrid = 4096;
    hipMemsetAsync(prop, 0, propBytes, stream);
    spmm_atomic<<<spmmGrid, blk, 0, stream>>>(ei, C, x, prop);
    gemm_lds<128, 4, true, true><<<gGemm, blk, 0, stream>>>(prop, W1, b1, h, NN);
    hipMemsetAsync(prop, 0, propBytes, stream);
    spmm_atomic<<<spmmGrid, blk, 0, stream>>>(ei, C, h, prop);
    gemm_lds<128, 4, true, true><<<gGemm, blk, 0, stream>>>(prop, W2, b2, h, NN);
    hipMemsetAsync(prop, 0, propBytes, stream);
    spmm_atomic<<<spmmGrid, blk, 0, stream>>>(ei, C, h, prop);
    gemm_lds<64, 2, false, true><<<gGemm, blk, 0, stream>>>(prop, W3, b3, out, NN);
  }
}

// Round 13
// 294.425 us; speedup vs baseline: 9.6552x; 1.0574x over previous
//
#include <hip/hip_runtime.h>

#define NN 50000
#define NE 800000
#define DIM 128
#define NB ((NN + 255) / 256)   // 196 scan chunks

// ================= CSR build (edge pattern reused for all 3 layers) =================
__global__ __launch_bounds__(256) void edge_histo_pos(const int* __restrict__ ei,
                                                      int* __restrict__ cnt,
                                                      int* __restrict__ pos) {
  int e = blockIdx.x * 256 + threadIdx.x;
  if (e >= NE) return;
  int r = ei[e], c = ei[NE + e];
  int p = -1;
  if ((unsigned)r < NN && (unsigned)c < NN) p = atomicAdd(&cnt[r], 1);
  pos[e] = p;   // coalesced
}

// ---- distributed 2-level exclusive scan ----
__global__ __launch_bounds__(256) void block_sums(const int* __restrict__ cnt,
                                                  int* __restrict__ bsum) {
  int i = blockIdx.x * 256 + threadIdx.x;
  int v = (i < NN) ? cnt[i] : 0;
#pragma unroll
  for (int off = 1; off < 64; off <<= 1) v += __shfl_xor(v, off, 64);
  __shared__ int ws[4];
  if ((threadIdx.x & 63) == 0) ws[threadIdx.x >> 6] = v;
  __syncthreads();
  if (threadIdx.x == 0) bsum[blockIdx.x] = ws[0] + ws[1] + ws[2] + ws[3];
}

__global__ __launch_bounds__(256) void scan_bsums(const int* __restrict__ bsum,
                                                  int* __restrict__ bbase) {
  int t = threadIdx.x;
  int v = (t < NB) ? bsum[t] : 0;
  int lane = t & 63, w = t >> 6;
  int inc = v;
#pragma unroll
  for (int off = 1; off < 64; off <<= 1) {
    int u = __shfl_up(inc, off, 64);
    if (lane >= off) inc += u;
  }
  __shared__ int ws[4];
  if (lane == 63) ws[w] = inc;
  __syncthreads();
  int wb = 0;
  for (int k = 0; k < w; ++k) wb += ws[k];
  if (t < NB) bbase[t] = wb + inc - v;
}

__global__ __launch_bounds__(256) void scan_final(const int* __restrict__ cnt,
                                                  const int* __restrict__ bbase,
                                                  int* __restrict__ rowStart) {
  int i = blockIdx.x * 256 + threadIdx.x;
  int v = (i < NN) ? cnt[i] : 0;
  int lane = threadIdx.x & 63, w = threadIdx.x >> 6;
  int inc = v;
#pragma unroll
  for (int off = 1; off < 64; off <<= 1) {
    int u = __shfl_up(inc, off, 64);
    if (lane >= off) inc += u;
  }
  __shared__ int ws[4];
  if (lane == 63) ws[w] = inc;
  __syncthreads();
  int wb = 0;
  for (int k = 0; k < w; ++k) wb += ws[k];
  int ex = bbase[blockIdx.x] + wb + inc - v;   // global exclusive prefix
  if (i < NN) rowStart[i] = ex;
  if (i == NN - 1) rowStart[NN] = ex + v;
}

// Atomic-free scatter: position precomputed, pure address math + scattered write.
__global__ __launch_bounds__(256) void edge_scatter(const int* __restrict__ ei,
                                                    const float* __restrict__ vals,
                                                    const int* __restrict__ rowStart,
                                                    const int* __restrict__ pos,
                                                    int2* __restrict__ cv) {
  int e = blockIdx.x * 256 + threadIdx.x;
  if (e >= NE) return;
  int p = pos[e];
  if (p < 0) return;
  int r = ei[e], c = ei[NE + e];
  cv[rowStart[r] + p] = make_int2(c, __float_as_int(vals[e]));
}

// ============ SpMM gather: D/4 lanes per row, regs accumulate, no atomics ============
// R12: unroll-8 was null, FETCH unchanged -> fabric-BW-bound at ~3.2-3.6 TB/s. Keep.
__device__ __forceinline__ void fma4(float v, const float4& x, float4& acc) {
  acc.x = fmaf(v, x.x, acc.x);
  acc.y = fmaf(v, x.y, acc.y);
  acc.z = fmaf(v, x.z, acc.z);
  acc.w = fmaf(v, x.w, acc.w);
}

template <int D, bool BIAS>
__global__ __launch_bounds__(256) void spmm_csr(const int* __restrict__ rowStart,
                                                const int2* __restrict__ cv,
                                                const float* __restrict__ h,
                                                const float* __restrict__ bias,
                                                float* __restrict__ out) {
  constexpr int L = D / 4;                      // lanes per row
  const int lane = threadIdx.x % L;
  const int r = blockIdx.x * (256 / L) + threadIdx.x / L;
  if (r >= NN) return;
  int p = rowStart[r], pend = rowStart[r + 1];
  float4 acc = BIAS ? ((const float4*)bias)[lane] : make_float4(0.f, 0.f, 0.f, 0.f);
  for (; p + 7 < pend; p += 8) {
    int2 e0 = cv[p],     e1 = cv[p + 1], e2 = cv[p + 2], e3 = cv[p + 3];
    int2 e4 = cv[p + 4], e5 = cv[p + 5], e6 = cv[p + 6], e7 = cv[p + 7];
    float4 x0 = ((const float4*)(h + (size_t)e0.x * D))[lane];
    float4 x1 = ((const float4*)(h + (size_t)e1.x * D))[lane];
    float4 x2 = ((const float4*)(h + (size_t)e2.x * D))[lane];
    float4 x3 = ((const float4*)(h + (size_t)e3.x * D))[lane];
    float4 x4 = ((const float4*)(h + (size_t)e4.x * D))[lane];
    float4 x5 = ((const float4*)(h + (size_t)e5.x * D))[lane];
    float4 x6 = ((const float4*)(h + (size_t)e6.x * D))[lane];
    float4 x7 = ((const float4*)(h + (size_t)e7.x * D))[lane];
    fma4(__int_as_float(e0.y), x0, acc);
    fma4(__int_as_float(e1.y), x1, acc);
    fma4(__int_as_float(e2.y), x2, acc);
    fma4(__int_as_float(e3.y), x3, acc);
    fma4(__int_as_float(e4.y), x4, acc);
    fma4(__int_as_float(e5.y), x5, acc);
    fma4(__int_as_float(e6.y), x6, acc);
    fma4(__int_as_float(e7.y), x7, acc);
  }
  for (; p + 3 < pend; p += 4) {
    int2 e0 = cv[p], e1 = cv[p + 1], e2 = cv[p + 2], e3 = cv[p + 3];
    float4 x0 = ((const float4*)(h + (size_t)e0.x * D))[lane];
    float4 x1 = ((const float4*)(h + (size_t)e1.x * D))[lane];
    float4 x2 = ((const float4*)(h + (size_t)e2.x * D))[lane];
    float4 x3 = ((const float4*)(h + (size_t)e3.x * D))[lane];
    fma4(__int_as_float(e0.y), x0, acc);
    fma4(__int_as_float(e1.y), x1, acc);
    fma4(__int_as_float(e2.y), x2, acc);
    fma4(__int_as_float(e3.y), x3, acc);
  }
  for (; p < pend; ++p) {
    int2 e0 = cv[p];
    float4 x0 = ((const float4*)(h + (size_t)e0.x * D))[lane];
    fma4(__int_as_float(e0.y), x0, acc);
  }
  ((float4*)(out + (size_t)r * D))[lane] = acc;
}

// ---------------- fallback: atomic scatter SpMM (if ws too small) ----------------
__global__ __launch_bounds__(256) void spmm_atomic(
    const int* __restrict__ ei, const float* __restrict__ vals,
    const float* __restrict__ h, float* __restrict__ prop) {
  const int lane32 = threadIdx.x & 31;
  int hw = blockIdx.x * (blockDim.x >> 5) + (threadIdx.x >> 5);
  const int stride = gridDim.x * (blockDim.x >> 5);
  for (int e = hw; e < NE; e += stride) {
    int r = ei[e], c = ei[NE + e];
    float v = vals[e];
    if ((unsigned)r >= NN || (unsigned)c >= NN) continue;
    float4 x = ((const float4*)(h + (size_t)c * DIM))[lane32];
    float* pp = prop + (size_t)r * DIM + lane32 * 4;
    unsafeAtomicAdd(pp + 0, v * x.x);
    unsafeAtomicAdd(pp + 1, v * x.y);
    unsafeAtomicAdd(pp + 2, v * x.z);
    unsafeAtomicAdd(pp + 3, v * x.w);
  }
}

// ========== All-LDS dense layer: W staged once per block, A-tile per iteration ======
// R12 analysis: ~43 us/GEMM from W global-load latency per chunk (R7: VALUBusy 23%).
// Inner loop now reads BOTH operands from LDS (ds_read_b128 + FMA only; compiler's
// fine-grained lgkmcnt scheduling is near-optimal per m97). W broadcast across
// row-groups (free); blocks grid-stride row tiles so W loads amortize.
// LDS: OUT=128: 64+16=80 KB (2 blk/CU); OUT=64: 32+16=48 KB (3 blk/CU).
// A must point into d_ws (tail-tile staging overruns < 16 KB into adjacent ws).
template <int OUT_DIM, int MR, bool NORM, bool BIAS>
__global__ __launch_bounds__(256) void gemm_lds2(
    const float* __restrict__ A, const float* __restrict__ W,
    const float* __restrict__ b, float* __restrict__ out, int n) {
  constexpr int JT = OUT_DIM / 4;      // threads along N (32 or 16)
  constexpr int RG = 256 / JT;         // row groups (8 or 16)
  constexpr int TILE_M = RG * MR;      // 32
  static_assert(TILE_M == 32, "staging loop assumes 32-row tile");
  __shared__ float Ws[DIM * OUT_DIM];  // 64 KB (128) / 32 KB (64)
  __shared__ float As[TILE_M * DIM];   // 16 KB, linear (gload_lds dest)

  const int tid = threadIdx.x;
  // ---- copy W -> LDS once per block (coalesced float4, ds_write_b128) ----
  for (int i = tid; i < DIM * OUT_DIM / 4; i += 256)
    ((float4*)Ws)[i] = ((const float4*)W)[i];

  const int j  = tid % JT;
  const int rg = tid / JT;
  float4 bv = make_float4(0.f, 0.f, 0.f, 0.f);
  if (BIAS) bv = ((const float4*)b)[j];
  const float* Wj = Ws + j * 4;

  const int ntiles = (n + TILE_M - 1) / TILE_M;
  for (int tile = blockIdx.x; tile < ntiles; tile += gridDim.x) {
    // ---- stage A tile -> As (linear dest + linear src, rule-21 compliant) ----
    const size_t gbase = (size_t)tile * TILE_M * DIM;
#pragma unroll
    for (int it = 0; it < 4; ++it) {
      const float* g = A + gbase + it * 1024 + tid * 4;
      auto* lp = (__attribute__((address_space(3))) char*)As + it * 4096 + (tid >> 6) * 1024;
      __builtin_amdgcn_global_load_lds((const __attribute__((address_space(1))) void*)g,
                                       (__attribute__((address_space(3))) void*)lp, 16, 0, 0);
    }
    asm volatile("s_waitcnt vmcnt(0)" ::: "memory");
    __syncthreads();   // A visible (and W on first iteration)

    float acc[MR][4];
#pragma unroll
    for (int i = 0; i < MR; ++i) {
      acc[i][0] = bv.x; acc[i][1] = bv.y; acc[i][2] = bv.z; acc[i][3] = bv.w;
    }

#pragma unroll 2
    for (int kk = 0; kk < DIM; kk += 4) {
      float4 w0 = *(const float4*)(Wj + (size_t)(kk + 0) * OUT_DIM);
      float4 w1 = *(const float4*)(Wj + (size_t)(kk + 1) * OUT_DIM);
      float4 w2 = *(const float4*)(Wj + (size_t)(kk + 2) * OUT_DIM);
      float4 w3 = *(const float4*)(Wj + (size_t)(kk + 3) * OUT_DIM);
      float4 a4[MR];
#pragma unroll
      for (int i = 0; i < MR; ++i)
        a4[i] = *(const float4*)(As + (rg * MR + i) * DIM + kk);
#pragma unroll
      for (int i = 0; i < MR; ++i) {
        acc[i][0] = fmaf(a4[i].x, w0.x, acc[i][0]);
        acc[i][1] = fmaf(a4[i].x, w0.y, acc[i][1]);
        acc[i][2] = fmaf(a4[i].x, w0.z, acc[i][2]);
        acc[i][3] = fmaf(a4[i].x, w0.w, acc[i][3]);
        acc[i][0] = fmaf(a4[i].y, w1.x, acc[i][0]);
        acc[i][1] = fmaf(a4[i].y, w1.y, acc[i][1]);
        acc[i][2] = fmaf(a4[i].y, w1.z, acc[i][2]);
        acc[i][3] = fmaf(a4[i].y, w1.w, acc[i][3]);
        acc[i][0] = fmaf(a4[i].z, w2.x, acc[i][0]);
        acc[i][1] = fmaf(a4[i].z, w2.y, acc[i][1]);
        acc[i][2] = fmaf(a4[i].z, w2.z, acc[i][2]);
        acc[i][3] = fmaf(a4[i].z, w2.w, acc[i][3]);
        acc[i][0] = fmaf(a4[i].w, w3.x, acc[i][0]);
        acc[i][1] = fmaf(a4[i].w, w3.y, acc[i][1]);
        acc[i][2] = fmaf(a4[i].w, w3.z, acc[i][2]);
        acc[i][3] = fmaf(a4[i].w, w3.w, acc[i][3]);
      }
    }

    const int row0 = tile * TILE_M + rg * MR;
#pragma unroll
    for (int i = 0; i < MR; ++i) {
      int row = row0 + i;
      if (NORM) {
        float v0 = fmaxf(acc[i][0], 0.f), v1 = fmaxf(acc[i][1], 0.f);
        float v2 = fmaxf(acc[i][2], 0.f), v3 = fmaxf(acc[i][3], 0.f);
        float s = v0 * v0 + v1 * v1 + v2 * v2 + v3 * v3;
#pragma unroll
        for (int off = JT / 2; off >= 1; off >>= 1) s += __shfl_xor(s, off, JT);
        float inv = 1.0f / fmaxf(sqrtf(s), 1e-12f);
        if (row < n) {
          float4 st = make_float4(v0 * inv, v1 * inv, v2 * inv, v3 * inv);
          ((float4*)(out + (size_t)row * OUT_DIM))[j] = st;
        }
      } else {
        if (row < n) {
          float4 st = make_float4(acc[i][0], acc[i][1], acc[i][2], acc[i][3]);
          ((float4*)(out + (size_t)row * OUT_DIM))[j] = st;
        }
      }
    }
    __syncthreads();   // all reads of As done before next tile's staging
  }
}

extern "C" void kernel_launch(void* const* d_in, const int* in_sizes, int n_in,
                              void* d_out, int out_size, void* d_ws, size_t ws_size,
                              hipStream_t stream) {
  const float* x  = (const float*)d_in[0];
  const int*   ei = (const int*)d_in[1];
  const float* C  = (const float*)d_in[2];
  const float* W1 = (const float*)d_in[3];
  const float* b1 = (const float*)d_in[4];
  const float* W2 = (const float*)d_in[5];
  const float* b2 = (const float*)d_in[6];
  const float* W3 = (const float*)d_in[7];
  const float* b3 = (const float*)d_in[8];
  float* out = (float*)d_out;

  // ---- workspace layout ----
  float* prop     = (float*)d_ws;                        // NN*DIM f32 (also g[NN*64])
  float* h        = prop + (size_t)NN * DIM;             // NN*DIM f32
  int*   rowStart = (int*)(h + (size_t)NN * DIM);        // NN+1 (+pad)
  int*   cnt      = rowStart + NN + 2;                   // NN
  int*   bsum     = cnt + NN;                            // 256
  int*   bbase    = bsum + 256;                          // 256
  int*   pos      = bbase + 256;                         // NE per-edge rank
  int2*  cv       = (int2*)(pos + NE);                   // NE packed (col,val)
  const size_t need = (size_t)(2 * NN * DIM) * 4 + (size_t)(2 * NN + 2 + 512) * 4 +
                      (size_t)NE * 4 + (size_t)NE * 8;

  const dim3 blk(256);
  const int g128 = 512;   // 2 blocks/CU (80 KB LDS), grid-stride over 1563 tiles
  const int g64  = 768;   // 3 blocks/CU (48 KB LDS)
  const int gEdge = (NE + 255) / 256;

  if (ws_size >= need) {
    // ---- build CSR once, reuse 3x ----
    hipMemsetAsync(cnt, 0, (size_t)NN * 4, stream);
    edge_histo_pos<<<gEdge, blk, 0, stream>>>(ei, cnt, pos);
    block_sums<<<NB, blk, 0, stream>>>(cnt, bsum);
    scan_bsums<<<1, blk, 0, stream>>>(bsum, bbase);
    scan_final<<<NB, blk, 0, stream>>>(cnt, bbase, rowStart);
    edge_scatter<<<gEdge, blk, 0, stream>>>(ei, C, rowStart, pos, cv);

    // layer 1: prop = C@x; h = norm(relu(prop@W1 + b1))   (gemm A always in ws)
    spmm_csr<128, false><<<(NN + 7) / 8, blk, 0, stream>>>(rowStart, cv, x, nullptr, prop);
    gemm_lds2<128, 4, true, true><<<g128, blk, 0, stream>>>(prop, W1, b1, h, NN);
    // layer 2
    spmm_csr<128, false><<<(NN + 7) / 8, blk, 0, stream>>>(rowStart, cv, h, nullptr, prop);
    gemm_lds2<128, 4, true, true><<<g128, blk, 0, stream>>>(prop, W2, b2, h, NN);
    // layer 3 reassociated: g = h@W3 (no bias); out = C@g + b3
    gemm_lds2<64, 2, false, false><<<g64, blk, 0, stream>>>(h, W3, nullptr, prop, NN);
    spmm_csr<64, true><<<(NN + 15) / 16, blk, 0, stream>>>(rowStart, cv, prop, b3, out);
  } else {
    // fallback: atomic scatter path (gemm A still in ws)
    const size_t propBytes = (size_t)NN * DIM * sizeof(float);
    const int spmmGrid = 4096;
    hipMemsetAsync(prop, 0, propBytes, stream);
    spmm_atomic<<<spmmGrid, blk, 0, stream>>>(ei, C, x, prop);
    gemm_lds2<128, 4, true, true><<<g128, blk, 0, stream>>>(prop, W1, b1, h, NN);
    hipMemsetAsync(prop, 0, propBytes, stream);
    spmm_atomic<<<spmmGrid, blk, 0, stream>>>(ei, C, h, prop);
    gemm_lds2<128, 4, true, true><<<g128, blk, 0, stream>>>(prop, W2, b2, h, NN);
    hipMemsetAsync(prop, 0, propBytes, stream);
    spmm_atomic<<<spmmGrid, blk, 0, stream>>>(ei, C, h, prop);
    gemm_lds2<64, 2, false, true><<<g64, blk, 0, stream>>>(prop, W3, b3, out, NN);
  }
}

// Round 14
// 250.095 us; speedup vs baseline: 11.3666x; 1.1773x over previous
//
#include <hip/hip_runtime.h>
#include <hip/hip_fp16.h>

#define NN 50000
#define NE 800000
#define DIM 128
#define NB ((NN + 255) / 256)   // 196 scan chunks

// ================= CSR build (edge pattern reused for all 3 layers) =================
__global__ __launch_bounds__(256) void edge_histo_pos(const int* __restrict__ ei,
                                                      int* __restrict__ cnt,
                                                      int* __restrict__ pos) {
  int e = blockIdx.x * 256 + threadIdx.x;
  if (e >= NE) return;
  int r = ei[e], c = ei[NE + e];
  int p = -1;
  if ((unsigned)r < NN && (unsigned)c < NN) p = atomicAdd(&cnt[r], 1);
  pos[e] = p;   // coalesced
}

// ---- distributed 2-level exclusive scan ----
__global__ __launch_bounds__(256) void block_sums(const int* __restrict__ cnt,
                                                  int* __restrict__ bsum) {
  int i = blockIdx.x * 256 + threadIdx.x;
  int v = (i < NN) ? cnt[i] : 0;
#pragma unroll
  for (int off = 1; off < 64; off <<= 1) v += __shfl_xor(v, off, 64);
  __shared__ int ws[4];
  if ((threadIdx.x & 63) == 0) ws[threadIdx.x >> 6] = v;
  __syncthreads();
  if (threadIdx.x == 0) bsum[blockIdx.x] = ws[0] + ws[1] + ws[2] + ws[3];
}

__global__ __launch_bounds__(256) void scan_bsums(const int* __restrict__ bsum,
                                                  int* __restrict__ bbase) {
  int t = threadIdx.x;
  int v = (t < NB) ? bsum[t] : 0;
  int lane = t & 63, w = t >> 6;
  int inc = v;
#pragma unroll
  for (int off = 1; off < 64; off <<= 1) {
    int u = __shfl_up(inc, off, 64);
    if (lane >= off) inc += u;
  }
  __shared__ int ws[4];
  if (lane == 63) ws[w] = inc;
  __syncthreads();
  int wb = 0;
  for (int k = 0; k < w; ++k) wb += ws[k];
  if (t < NB) bbase[t] = wb + inc - v;
}

__global__ __launch_bounds__(256) void scan_final(const int* __restrict__ cnt,
                                                  const int* __restrict__ bbase,
                                                  int* __restrict__ rowStart) {
  int i = blockIdx.x * 256 + threadIdx.x;
  int v = (i < NN) ? cnt[i] : 0;
  int lane = threadIdx.x & 63, w = threadIdx.x >> 6;
  int inc = v;
#pragma unroll
  for (int off = 1; off < 64; off <<= 1) {
    int u = __shfl_up(inc, off, 64);
    if (lane >= off) inc += u;
  }
  __shared__ int ws[4];
  if (lane == 63) ws[w] = inc;
  __syncthreads();
  int wb = 0;
  for (int k = 0; k < w; ++k) wb += ws[k];
  int ex = bbase[blockIdx.x] + wb + inc - v;   // global exclusive prefix
  if (i < NN) rowStart[i] = ex;
  if (i == NN - 1) rowStart[NN] = ex + v;
}

// Atomic-free scatter: position precomputed, pure address math + scattered write.
__global__ __launch_bounds__(256) void edge_scatter(const int* __restrict__ ei,
                                                    const float* __restrict__ vals,
                                                    const int* __restrict__ rowStart,
                                                    const int* __restrict__ pos,
                                                    int2* __restrict__ cv) {
  int e = blockIdx.x * 256 + threadIdx.x;
  if (e >= NE) return;
  int p = pos[e];
  if (p < 0) return;
  int r = ei[e], c = ei[NE + e];
  cv[rowStart[r] + p] = make_int2(c, __float_as_int(vals[e]));
}

// ---- fp32 -> fp16 conversion (x and produced features; halves SpMM gather bytes) ----
__global__ __launch_bounds__(256) void f32_to_f16(const float* __restrict__ src,
                                                  __half* __restrict__ dst, int n4) {
  int i = blockIdx.x * 256 + threadIdx.x;
  if (i >= n4) return;
  float4 v = ((const float4*)src)[i];
  __half2 lo = __floats2half2_rn(v.x, v.y);
  __half2 hi = __floats2half2_rn(v.z, v.w);
  uint2 u;
  u.x = *(unsigned int*)&lo;
  u.y = *(unsigned int*)&hi;
  ((uint2*)dst)[i] = u;
}

// ============ SpMM gather (fp16 source): D/4 lanes/row, 8B/lane gathers ============
// R12/R13: fp32 gather is fabric-fill-bound (FETCH 177MB = 8-XCD compulsory
// replication, 3.6 TB/s). fp16 halves the gathered bytes; fp32 accumulate.
__device__ __forceinline__ void fma4(float v, const float4& x, float4& acc) {
  acc.x = fmaf(v, x.x, acc.x);
  acc.y = fmaf(v, x.y, acc.y);
  acc.z = fmaf(v, x.z, acc.z);
  acc.w = fmaf(v, x.w, acc.w);
}

__device__ __forceinline__ float4 cvt4(uint2 raw) {
  __half2 a = *reinterpret_cast<__half2*>(&raw.x);
  __half2 b = *reinterpret_cast<__half2*>(&raw.y);
  float2 fa = __half22float2(a), fb = __half22float2(b);
  return make_float4(fa.x, fa.y, fb.x, fb.y);
}

template <int D, bool BIAS>
__global__ __launch_bounds__(256) void spmm_csr_h(const int* __restrict__ rowStart,
                                                  const int2* __restrict__ cv,
                                                  const __half* __restrict__ h,
                                                  const float* __restrict__ bias,
                                                  float* __restrict__ out) {
  constexpr int L = D / 4;                      // lanes per row
  const int lane = threadIdx.x % L;
  const int r = blockIdx.x * (256 / L) + threadIdx.x / L;
  if (r >= NN) return;
  int p = rowStart[r], pend = rowStart[r + 1];
  float4 acc = BIAS ? ((const float4*)bias)[lane] : make_float4(0.f, 0.f, 0.f, 0.f);
  for (; p + 7 < pend; p += 8) {
    int2 e0 = cv[p],     e1 = cv[p + 1], e2 = cv[p + 2], e3 = cv[p + 3];
    int2 e4 = cv[p + 4], e5 = cv[p + 5], e6 = cv[p + 6], e7 = cv[p + 7];
    uint2 r0 = ((const uint2*)(h + (size_t)e0.x * D))[lane];
    uint2 r1 = ((const uint2*)(h + (size_t)e1.x * D))[lane];
    uint2 r2 = ((const uint2*)(h + (size_t)e2.x * D))[lane];
    uint2 r3 = ((const uint2*)(h + (size_t)e3.x * D))[lane];
    uint2 r4 = ((const uint2*)(h + (size_t)e4.x * D))[lane];
    uint2 r5 = ((const uint2*)(h + (size_t)e5.x * D))[lane];
    uint2 r6 = ((const uint2*)(h + (size_t)e6.x * D))[lane];
    uint2 r7 = ((const uint2*)(h + (size_t)e7.x * D))[lane];
    fma4(__int_as_float(e0.y), cvt4(r0), acc);
    fma4(__int_as_float(e1.y), cvt4(r1), acc);
    fma4(__int_as_float(e2.y), cvt4(r2), acc);
    fma4(__int_as_float(e3.y), cvt4(r3), acc);
    fma4(__int_as_float(e4.y), cvt4(r4), acc);
    fma4(__int_as_float(e5.y), cvt4(r5), acc);
    fma4(__int_as_float(e6.y), cvt4(r6), acc);
    fma4(__int_as_float(e7.y), cvt4(r7), acc);
  }
  for (; p < pend; ++p) {
    int2 e0 = cv[p];
    uint2 r0 = ((const uint2*)(h + (size_t)e0.x * D))[lane];
    fma4(__int_as_float(e0.y), cvt4(r0), acc);
  }
  ((float4*)(out + (size_t)r * D))[lane] = acc;
}

// ---------------- fallback: atomic scatter SpMM fp32 (if ws too small) ----------------
__global__ __launch_bounds__(256) void spmm_atomic(
    const int* __restrict__ ei, const float* __restrict__ vals,
    const float* __restrict__ h, float* __restrict__ prop) {
  const int lane32 = threadIdx.x & 31;
  int hw = blockIdx.x * (blockDim.x >> 5) + (threadIdx.x >> 5);
  const int stride = gridDim.x * (blockDim.x >> 5);
  for (int e = hw; e < NE; e += stride) {
    int r = ei[e], c = ei[NE + e];
    float v = vals[e];
    if ((unsigned)r >= NN || (unsigned)c >= NN) continue;
    float4 x = ((const float4*)(h + (size_t)c * DIM))[lane32];
    float* pp = prop + (size_t)r * DIM + lane32 * 4;
    unsafeAtomicAdd(pp + 0, v * x.x);
    unsafeAtomicAdd(pp + 1, v * x.y);
    unsafeAtomicAdd(pp + 2, v * x.z);
    unsafeAtomicAdd(pp + 3, v * x.w);
  }
}

// ========== All-LDS dense layer; optional fp16 output (for gathered arrays) ==========
// Inner loop: ds_read_b128 x8 + 64 FMA per 4-k chunk, both operands in LDS.
// HOUT=true stores half4 (8B) rows for the next layer's fp16 gather.
template <int OUT_DIM, int MR, bool NORM, bool BIAS, bool HOUT>
__global__ __launch_bounds__(256) void gemm_lds2(
    const float* __restrict__ A, const float* __restrict__ W,
    const float* __restrict__ b, void* __restrict__ outv, int n) {
  constexpr int JT = OUT_DIM / 4;      // threads along N (32 or 16)
  constexpr int RG = 256 / JT;         // row groups (8 or 16)
  constexpr int TILE_M = RG * MR;      // 32
  static_assert(TILE_M == 32, "staging loop assumes 32-row tile");
  __shared__ float Ws[DIM * OUT_DIM];  // 64 KB (128) / 32 KB (64)
  __shared__ float As[TILE_M * DIM];   // 16 KB, linear (gload_lds dest)

  const int tid = threadIdx.x;
  for (int i = tid; i < DIM * OUT_DIM / 4; i += 256)
    ((float4*)Ws)[i] = ((const float4*)W)[i];

  const int j  = tid % JT;
  const int rg = tid / JT;
  float4 bv = make_float4(0.f, 0.f, 0.f, 0.f);
  if (BIAS) bv = ((const float4*)b)[j];
  const float* Wj = Ws + j * 4;

  const int ntiles = (n + TILE_M - 1) / TILE_M;
  for (int tile = blockIdx.x; tile < ntiles; tile += gridDim.x) {
    const size_t gbase = (size_t)tile * TILE_M * DIM;
#pragma unroll
    for (int it = 0; it < 4; ++it) {
      const float* g = A + gbase + it * 1024 + tid * 4;
      auto* lp = (__attribute__((address_space(3))) char*)As + it * 4096 + (tid >> 6) * 1024;
      __builtin_amdgcn_global_load_lds((const __attribute__((address_space(1))) void*)g,
                                       (__attribute__((address_space(3))) void*)lp, 16, 0, 0);
    }
    asm volatile("s_waitcnt vmcnt(0)" ::: "memory");
    __syncthreads();

    float acc[MR][4];
#pragma unroll
    for (int i = 0; i < MR; ++i) {
      acc[i][0] = bv.x; acc[i][1] = bv.y; acc[i][2] = bv.z; acc[i][3] = bv.w;
    }

#pragma unroll 2
    for (int kk = 0; kk < DIM; kk += 4) {
      float4 w0 = *(const float4*)(Wj + (size_t)(kk + 0) * OUT_DIM);
      float4 w1 = *(const float4*)(Wj + (size_t)(kk + 1) * OUT_DIM);
      float4 w2 = *(const float4*)(Wj + (size_t)(kk + 2) * OUT_DIM);
      float4 w3 = *(const float4*)(Wj + (size_t)(kk + 3) * OUT_DIM);
      float4 a4[MR];
#pragma unroll
      for (int i = 0; i < MR; ++i)
        a4[i] = *(const float4*)(As + (rg * MR + i) * DIM + kk);
#pragma unroll
      for (int i = 0; i < MR; ++i) {
        acc[i][0] = fmaf(a4[i].x, w0.x, acc[i][0]);
        acc[i][1] = fmaf(a4[i].x, w0.y, acc[i][1]);
        acc[i][2] = fmaf(a4[i].x, w0.z, acc[i][2]);
        acc[i][3] = fmaf(a4[i].x, w0.w, acc[i][3]);
        acc[i][0] = fmaf(a4[i].y, w1.x, acc[i][0]);
        acc[i][1] = fmaf(a4[i].y, w1.y, acc[i][1]);
        acc[i][2] = fmaf(a4[i].y, w1.z, acc[i][2]);
        acc[i][3] = fmaf(a4[i].y, w1.w, acc[i][3]);
        acc[i][0] = fmaf(a4[i].z, w2.x, acc[i][0]);
        acc[i][1] = fmaf(a4[i].z, w2.y, acc[i][1]);
        acc[i][2] = fmaf(a4[i].z, w2.z, acc[i][2]);
        acc[i][3] = fmaf(a4[i].z, w2.w, acc[i][3]);
        acc[i][0] = fmaf(a4[i].w, w3.x, acc[i][0]);
        acc[i][1] = fmaf(a4[i].w, w3.y, acc[i][1]);
        acc[i][2] = fmaf(a4[i].w, w3.z, acc[i][2]);
        acc[i][3] = fmaf(a4[i].w, w3.w, acc[i][3]);
      }
    }

    const int row0 = tile * TILE_M + rg * MR;
#pragma unroll
    for (int i = 0; i < MR; ++i) {
      int row = row0 + i;
      float v0 = acc[i][0], v1 = acc[i][1], v2 = acc[i][2], v3 = acc[i][3];
      if (NORM) {
        v0 = fmaxf(v0, 0.f); v1 = fmaxf(v1, 0.f);
        v2 = fmaxf(v2, 0.f); v3 = fmaxf(v3, 0.f);
        float s = v0 * v0 + v1 * v1 + v2 * v2 + v3 * v3;
#pragma unroll
        for (int off = JT / 2; off >= 1; off >>= 1) s += __shfl_xor(s, off, JT);
        float inv = 1.0f / fmaxf(sqrtf(s), 1e-12f);
        v0 *= inv; v1 *= inv; v2 *= inv; v3 *= inv;
      }
      if (row < n) {
        if (HOUT) {
          __half2 lo = __floats2half2_rn(v0, v1);
          __half2 hi = __floats2half2_rn(v2, v3);
          uint2 u;
          u.x = *(unsigned int*)&lo;
          u.y = *(unsigned int*)&hi;
          ((uint2*)((__half*)outv + (size_t)row * OUT_DIM))[j] = u;
        } else {
          ((float4*)((float*)outv + (size_t)row * OUT_DIM))[j] =
              make_float4(v0, v1, v2, v3);
        }
      }
    }
    __syncthreads();
  }
}

extern "C" void kernel_launch(void* const* d_in, const int* in_sizes, int n_in,
                              void* d_out, int out_size, void* d_ws, size_t ws_size,
                              hipStream_t stream) {
  const float* x  = (const float*)d_in[0];
  const int*   ei = (const int*)d_in[1];
  const float* C  = (const float*)d_in[2];
  const float* W1 = (const float*)d_in[3];
  const float* b1 = (const float*)d_in[4];
  const float* W2 = (const float*)d_in[5];
  const float* b2 = (const float*)d_in[6];
  const float* W3 = (const float*)d_in[7];
  const float* b3 = (const float*)d_in[8];
  float* out = (float*)d_out;

  // ---- workspace layout (all offsets 8B-aligned) ----
  float*  prop     = (float*)d_ws;                          // NN*DIM f32
  float*  h2       = prop + (size_t)NN * DIM;               // NN*DIM f32
  __half* x16      = (__half*)(h2 + (size_t)NN * DIM);      // NN*DIM f16 (reused as g16)
  __half* h16      = x16 + (size_t)NN * DIM;                // NN*DIM f16
  int*    rowStart = (int*)(h16 + (size_t)NN * DIM);        // NN+2
  int*    cnt      = rowStart + NN + 2;                     // NN
  int*    bsum     = cnt + NN;                              // 256
  int*    bbase    = bsum + 256;                            // 256
  int*    pos      = bbase + 256;                           // NE
  int2*   cv       = (int2*)(pos + NE);                     // NE (col,val)
  const size_t need = (size_t)(2 * NN * DIM) * 4 + (size_t)(2 * NN * DIM) * 2 +
                      (size_t)(2 * NN + 2 + 512) * 4 + (size_t)NE * 4 + (size_t)NE * 8;

  const dim3 blk(256);
  const int g128 = 512;   // 2 blocks/CU (80 KB LDS), grid-stride tiles
  const int g64  = 768;   // 3 blocks/CU (48 KB LDS)
  const int gEdge = (NE + 255) / 256;

  if (ws_size >= need) {
    // x -> fp16 (independent of CSR build)
    f32_to_f16<<<(NN * DIM / 4 + 255) / 256, blk, 0, stream>>>(x, x16, NN * DIM / 4);
    // ---- build CSR once, reuse 3x ----
    hipMemsetAsync(cnt, 0, (size_t)NN * 4, stream);
    edge_histo_pos<<<gEdge, blk, 0, stream>>>(ei, cnt, pos);
    block_sums<<<NB, blk, 0, stream>>>(cnt, bsum);
    scan_bsums<<<1, blk, 0, stream>>>(bsum, bbase);
    scan_final<<<NB, blk, 0, stream>>>(cnt, bbase, rowStart);
    edge_scatter<<<gEdge, blk, 0, stream>>>(ei, C, rowStart, pos, cv);

    // layer 1: prop = C@x16; h16 = fp16(norm(relu(prop@W1 + b1)))
    spmm_csr_h<128, false><<<(NN + 7) / 8, blk, 0, stream>>>(rowStart, cv, x16, nullptr, prop);
    gemm_lds2<128, 4, true, true, true><<<g128, blk, 0, stream>>>(prop, W1, b1, h16, NN);
    // layer 2: prop = C@h16; h2 = fp32(norm(relu(prop@W2 + b2)))
    spmm_csr_h<128, false><<<(NN + 7) / 8, blk, 0, stream>>>(rowStart, cv, h16, nullptr, prop);
    gemm_lds2<128, 4, true, true, false><<<g128, blk, 0, stream>>>(prop, W2, b2, h2, NN);
    // layer 3 reassociated: g16 = fp16(h2@W3); out = C@g16 + b3
    __half* g16 = x16;   // reuse (x16 dead after layer 1)
    gemm_lds2<64, 2, false, false, true><<<g64, blk, 0, stream>>>(h2, W3, nullptr, g16, NN);
    spmm_csr_h<64, true><<<(NN + 15) / 16, blk, 0, stream>>>(rowStart, cv, g16, b3, out);
  } else {
    // fallback: fp32 atomic scatter path
    const size_t propBytes = (size_t)NN * DIM * sizeof(float);
    const int spmmGrid = 4096;
    float* h = h2;
    hipMemsetAsync(prop, 0, propBytes, stream);
    spmm_atomic<<<spmmGrid, blk, 0, stream>>>(ei, C, x, prop);
    gemm_lds2<128, 4, true, true, false><<<g128, blk, 0, stream>>>(prop, W1, b1, h, NN);
    hipMemsetAsync(prop, 0, propBytes, stream);
    spmm_atomic<<<spmmGrid, blk, 0, stream>>>(ei, C, h, prop);
    gemm_lds2<128, 4, true, true, false><<<g128, blk, 0, stream>>>(prop, W2, b2, h, NN);
    hipMemsetAsync(prop, 0, propBytes, stream);
    spmm_atomic<<<spmmGrid, blk, 0, stream>>>(ei, C, h, prop);
    gemm_lds2<64, 2, false, true, false><<<g64, blk, 0, stream>>>(prop, W3, b3, out, NN);
  }
}

// Round 15
// 197.264 us; speedup vs baseline: 14.4108x; 1.2678x over previous
//
#include <hip/hip_runtime.h>
#include <hip/hip_fp16.h>

#define NN 50000
#define NE 800000
#define DIM 128
#define NB ((NN + 255) / 256)   // 196 scan chunks

typedef _Float16 half8 __attribute__((ext_vector_type(8)));
typedef float f32x4 __attribute__((ext_vector_type(4)));

// ================= CSR build (edge pattern reused for all 3 layers) =================
__global__ __launch_bounds__(256) void edge_histo_pos(const int* __restrict__ ei,
                                                      int* __restrict__ cnt,
                                                      int* __restrict__ pos) {
  int e = blockIdx.x * 256 + threadIdx.x;
  if (e >= NE) return;
  int r = ei[e], c = ei[NE + e];
  int p = -1;
  if ((unsigned)r < NN && (unsigned)c < NN) p = atomicAdd(&cnt[r], 1);
  pos[e] = p;
}

__global__ __launch_bounds__(256) void block_sums(const int* __restrict__ cnt,
                                                  int* __restrict__ bsum) {
  int i = blockIdx.x * 256 + threadIdx.x;
  int v = (i < NN) ? cnt[i] : 0;
#pragma unroll
  for (int off = 1; off < 64; off <<= 1) v += __shfl_xor(v, off, 64);
  __shared__ int ws[4];
  if ((threadIdx.x & 63) == 0) ws[threadIdx.x >> 6] = v;
  __syncthreads();
  if (threadIdx.x == 0) bsum[blockIdx.x] = ws[0] + ws[1] + ws[2] + ws[3];
}

__global__ __launch_bounds__(256) void scan_bsums(const int* __restrict__ bsum,
                                                  int* __restrict__ bbase) {
  int t = threadIdx.x;
  int v = (t < NB) ? bsum[t] : 0;
  int lane = t & 63, w = t >> 6;
  int inc = v;
#pragma unroll
  for (int off = 1; off < 64; off <<= 1) {
    int u = __shfl_up(inc, off, 64);
    if (lane >= off) inc += u;
  }
  __shared__ int ws[4];
  if (lane == 63) ws[w] = inc;
  __syncthreads();
  int wb = 0;
  for (int k = 0; k < w; ++k) wb += ws[k];
  if (t < NB) bbase[t] = wb + inc - v;
}

__global__ __launch_bounds__(256) void scan_final(const int* __restrict__ cnt,
                                                  const int* __restrict__ bbase,
                                                  int* __restrict__ rowStart) {
  int i = blockIdx.x * 256 + threadIdx.x;
  int v = (i < NN) ? cnt[i] : 0;
  int lane = threadIdx.x & 63, w = threadIdx.x >> 6;
  int inc = v;
#pragma unroll
  for (int off = 1; off < 64; off <<= 1) {
    int u = __shfl_up(inc, off, 64);
    if (lane >= off) inc += u;
  }
  __shared__ int ws[4];
  if (lane == 63) ws[w] = inc;
  __syncthreads();
  int wb = 0;
  for (int k = 0; k < w; ++k) wb += ws[k];
  int ex = bbase[blockIdx.x] + wb + inc - v;
  if (i < NN) rowStart[i] = ex;
  if (i == NN - 1) rowStart[NN] = ex + v;
}

__global__ __launch_bounds__(256) void edge_scatter(const int* __restrict__ ei,
                                                    const float* __restrict__ vals,
                                                    const int* __restrict__ rowStart,
                                                    const int* __restrict__ pos,
                                                    int2* __restrict__ cv) {
  int e = blockIdx.x * 256 + threadIdx.x;
  if (e >= NE) return;
  int p = pos[e];
  if (p < 0) return;
  int r = ei[e], c = ei[NE + e];
  cv[rowStart[r] + p] = make_int2(c, __float_as_int(vals[e]));
}

// ---- fp32 -> fp16 ----
__global__ __launch_bounds__(256) void f32_to_f16(const float* __restrict__ src,
                                                  __half* __restrict__ dst, int n4) {
  int i = blockIdx.x * 256 + threadIdx.x;
  if (i >= n4) return;
  float4 v = ((const float4*)src)[i];
  __half2 lo = __floats2half2_rn(v.x, v.y);
  __half2 hi = __floats2half2_rn(v.z, v.w);
  uint2 u;
  u.x = *(unsigned int*)&lo;
  u.y = *(unsigned int*)&hi;
  ((uint2*)dst)[i] = u;
}

// ---- pack W [K x N] fp32 row-major -> fp16 MFMA-fragment-major ----
// Wp[((kt*NC + ct)*64 + lane)*8 + j] = W[kt*32 + (lane>>4)*8 + j][ct*16 + (lane&15)]
// A-frag load uses the SAME (lane>>4, j) -> k bijection, so the pairing is consistent.
__global__ __launch_bounds__(256) void pack_w(const float* __restrict__ W,
                                              __half* __restrict__ Wp, int N, int total) {
  int idx = blockIdx.x * 256 + threadIdx.x;
  if (idx >= total) return;
  int j = idx & 7, lane = (idx >> 3) & 63, ctkt = idx >> 9;
  int NC = N / 16;
  int kt = ctkt / NC, ct = ctkt - kt * NC;
  int k = kt * 32 + ((lane >> 4) << 3) + j;
  int n = ct * 16 + (lane & 15);
  Wp[idx] = __float2half(W[k * N + n]);
}

// ============ SpMM gather (fp16 source); fp16 or fp32 output ============
__device__ __forceinline__ void fma4(float v, const float4& x, float4& acc) {
  acc.x = fmaf(v, x.x, acc.x);
  acc.y = fmaf(v, x.y, acc.y);
  acc.z = fmaf(v, x.z, acc.z);
  acc.w = fmaf(v, x.w, acc.w);
}

__device__ __forceinline__ float4 cvt4(uint2 raw) {
  __half2 a = *reinterpret_cast<__half2*>(&raw.x);
  __half2 b = *reinterpret_cast<__half2*>(&raw.y);
  float2 fa = __half22float2(a), fb = __half22float2(b);
  return make_float4(fa.x, fa.y, fb.x, fb.y);
}

template <int D, bool BIAS, bool HOUT>
__global__ __launch_bounds__(256) void spmm_csr_h(const int* __restrict__ rowStart,
                                                  const int2* __restrict__ cv,
                                                  const __half* __restrict__ h,
                                                  const float* __restrict__ bias,
                                                  void* __restrict__ outv) {
  constexpr int L = D / 4;
  const int lane = threadIdx.x % L;
  const int r = blockIdx.x * (256 / L) + threadIdx.x / L;
  if (r >= NN) return;
  int p = rowStart[r], pend = rowStart[r + 1];
  float4 acc = BIAS ? ((const float4*)bias)[lane] : make_float4(0.f, 0.f, 0.f, 0.f);
  for (; p + 7 < pend; p += 8) {
    int2 e0 = cv[p],     e1 = cv[p + 1], e2 = cv[p + 2], e3 = cv[p + 3];
    int2 e4 = cv[p + 4], e5 = cv[p + 5], e6 = cv[p + 6], e7 = cv[p + 7];
    uint2 r0 = ((const uint2*)(h + (size_t)e0.x * D))[lane];
    uint2 r1 = ((const uint2*)(h + (size_t)e1.x * D))[lane];
    uint2 r2 = ((const uint2*)(h + (size_t)e2.x * D))[lane];
    uint2 r3 = ((const uint2*)(h + (size_t)e3.x * D))[lane];
    uint2 r4 = ((const uint2*)(h + (size_t)e4.x * D))[lane];
    uint2 r5 = ((const uint2*)(h + (size_t)e5.x * D))[lane];
    uint2 r6 = ((const uint2*)(h + (size_t)e6.x * D))[lane];
    uint2 r7 = ((const uint2*)(h + (size_t)e7.x * D))[lane];
    fma4(__int_as_float(e0.y), cvt4(r0), acc);
    fma4(__int_as_float(e1.y), cvt4(r1), acc);
    fma4(__int_as_float(e2.y), cvt4(r2), acc);
    fma4(__int_as_float(e3.y), cvt4(r3), acc);
    fma4(__int_as_float(e4.y), cvt4(r4), acc);
    fma4(__int_as_float(e5.y), cvt4(r5), acc);
    fma4(__int_as_float(e6.y), cvt4(r6), acc);
    fma4(__int_as_float(e7.y), cvt4(r7), acc);
  }
  for (; p < pend; ++p) {
    int2 e0 = cv[p];
    uint2 r0 = ((const uint2*)(h + (size_t)e0.x * D))[lane];
    fma4(__int_as_float(e0.y), cvt4(r0), acc);
  }
  if (HOUT) {
    __half2 lo = __floats2half2_rn(acc.x, acc.y);
    __half2 hi = __floats2half2_rn(acc.z, acc.w);
    uint2 u;
    u.x = *(unsigned int*)&lo;
    u.y = *(unsigned int*)&hi;
    ((uint2*)((__half*)outv + (size_t)r * D))[lane] = u;
  } else {
    ((float4*)((float*)outv + (size_t)r * D))[lane] = acc;
  }
}

// ============ MFMA GEMM: out16 = A16 @ Wp (+b) (+ReLU +L2 norm), fp16 out ============
// Wave = 16 rows x NOUT cols; 4 waves/block = 64-row tile. K=128 in 4 steps of 32.
// C/D layout (m89): col = lane&15, row = (lane>>4)*4 + reg.
template <int NOUT, bool NORM, bool BIAS>
__global__ __launch_bounds__(256) void gemm_mfma(const __half* __restrict__ A,
                                                 const __half* __restrict__ Wp,
                                                 const float* __restrict__ b,
                                                 __half* __restrict__ out, int n) {
  constexpr int NC = NOUT / 16;   // col-tiles (8 or 4)
  constexpr int KT = DIM / 32;    // 4
  __shared__ __half Ws[KT * NC * 64 * 8];   // 32 KB (128) / 16 KB (64)
  const int tid = threadIdx.x;
  for (int i = tid; i < KT * NC * 64; i += 256)
    ((half8*)Ws)[i] = ((const half8*)Wp)[i];
  __syncthreads();

  const int wid = tid >> 6, lane = tid & 63;
  const int colbase = lane & 15;
  const int kgrp = lane >> 4;
  const int ntiles = (n + 63) >> 6;

  for (int tile = blockIdx.x; tile < ntiles; tile += gridDim.x) {
    const int row0 = tile * 64 + wid * 16;
    int rowA = row0 + colbase;            // A-row for this lane (lane&15)
    if (rowA > n - 1) rowA = n - 1;       // clamp; stores are guarded
    const half8* Arow = (const half8*)(A + (size_t)rowA * DIM);

    f32x4 acc[NC];
#pragma unroll
    for (int ct = 0; ct < NC; ++ct) {
      float bv = BIAS ? b[ct * 16 + colbase] : 0.f;
      acc[ct] = (f32x4){bv, bv, bv, bv};
    }

#pragma unroll
    for (int kt = 0; kt < KT; ++kt) {
      half8 af = Arow[kt * 4 + kgrp];     // 8 contiguous k-elems (16B)
#pragma unroll
      for (int ct = 0; ct < NC; ++ct) {
        half8 bf = ((const half8*)Ws)[(kt * NC + ct) * 64 + lane];
        acc[ct] = __builtin_amdgcn_mfma_f32_16x16x32_f16(af, bf, acc[ct], 0, 0, 0);
      }
    }

#pragma unroll
    for (int j = 0; j < 4; ++j) {
      int row = row0 + (kgrp << 2) + j;
      if (NORM) {
        float s = 0.f;
#pragma unroll
        for (int ct = 0; ct < NC; ++ct) {
          float v = fmaxf(acc[ct][j], 0.f);
          s = fmaf(v, v, s);
        }
        s += __shfl_xor(s, 1); s += __shfl_xor(s, 2);
        s += __shfl_xor(s, 4); s += __shfl_xor(s, 8);   // 16-lane group = one row set
        float inv = 1.0f / fmaxf(sqrtf(s), 1e-12f);
        if (row < n) {
#pragma unroll
          for (int ct = 0; ct < NC; ++ct)
            out[(size_t)row * NOUT + ct * 16 + colbase] =
                __float2half(fmaxf(acc[ct][j], 0.f) * inv);
        }
      } else {
        if (row < n) {
#pragma unroll
          for (int ct = 0; ct < NC; ++ct)
            out[(size_t)row * NOUT + ct * 16 + colbase] = __float2half(acc[ct][j]);
        }
      }
    }
  }
}

// ---------------- fallback kernels (fp32 path, if ws too small) ----------------
__global__ __launch_bounds__(256) void spmm_atomic(
    const int* __restrict__ ei, const float* __restrict__ vals,
    const float* __restrict__ h, float* __restrict__ prop) {
  const int lane32 = threadIdx.x & 31;
  int hw = blockIdx.x * (blockDim.x >> 5) + (threadIdx.x >> 5);
  const int stride = gridDim.x * (blockDim.x >> 5);
  for (int e = hw; e < NE; e += stride) {
    int r = ei[e], c = ei[NE + e];
    float v = vals[e];
    if ((unsigned)r >= NN || (unsigned)c >= NN) continue;
    float4 x = ((const float4*)(h + (size_t)c * DIM))[lane32];
    float* pp = prop + (size_t)r * DIM + lane32 * 4;
    unsafeAtomicAdd(pp + 0, v * x.x);
    unsafeAtomicAdd(pp + 1, v * x.y);
    unsafeAtomicAdd(pp + 2, v * x.z);
    unsafeAtomicAdd(pp + 3, v * x.w);
  }
}

template <int OUT_DIM, int MR, bool NORM, bool BIAS>
__global__ __launch_bounds__(256) void gemm_lds2(
    const float* __restrict__ A, const float* __restrict__ W,
    const float* __restrict__ b, float* __restrict__ out, int n) {
  constexpr int JT = OUT_DIM / 4;
  constexpr int RG = 256 / JT;
  constexpr int TILE_M = RG * MR;
  __shared__ float Ws[DIM * OUT_DIM];
  __shared__ float As[TILE_M * DIM];
  const int tid = threadIdx.x;
  for (int i = tid; i < DIM * OUT_DIM / 4; i += 256)
    ((float4*)Ws)[i] = ((const float4*)W)[i];
  const int j = tid % JT, rg = tid / JT;
  float4 bv = make_float4(0.f, 0.f, 0.f, 0.f);
  if (BIAS) bv = ((const float4*)b)[j];
  const float* Wj = Ws + j * 4;
  const int ntiles = (n + TILE_M - 1) / TILE_M;
  for (int tile = blockIdx.x; tile < ntiles; tile += gridDim.x) {
    const size_t gbase = (size_t)tile * TILE_M * DIM;
#pragma unroll
    for (int it = 0; it < 4; ++it) {
      const float* g = A + gbase + it * 1024 + tid * 4;
      auto* lp = (__attribute__((address_space(3))) char*)As + it * 4096 + (tid >> 6) * 1024;
      __builtin_amdgcn_global_load_lds((const __attribute__((address_space(1))) void*)g,
                                       (__attribute__((address_space(3))) void*)lp, 16, 0, 0);
    }
    asm volatile("s_waitcnt vmcnt(0)" ::: "memory");
    __syncthreads();
    float acc[MR][4];
#pragma unroll
    for (int i = 0; i < MR; ++i) {
      acc[i][0] = bv.x; acc[i][1] = bv.y; acc[i][2] = bv.z; acc[i][3] = bv.w;
    }
#pragma unroll 2
    for (int kk = 0; kk < DIM; kk += 4) {
      float4 w0 = *(const float4*)(Wj + (size_t)(kk + 0) * OUT_DIM);
      float4 w1 = *(const float4*)(Wj + (size_t)(kk + 1) * OUT_DIM);
      float4 w2 = *(const float4*)(Wj + (size_t)(kk + 2) * OUT_DIM);
      float4 w3 = *(const float4*)(Wj + (size_t)(kk + 3) * OUT_DIM);
      float4 a4[MR];
#pragma unroll
      for (int i = 0; i < MR; ++i)
        a4[i] = *(const float4*)(As + (rg * MR + i) * DIM + kk);
#pragma unroll
      for (int i = 0; i < MR; ++i) {
        acc[i][0] = fmaf(a4[i].x, w0.x, acc[i][0]);
        acc[i][1] = fmaf(a4[i].x, w0.y, acc[i][1]);
        acc[i][2] = fmaf(a4[i].x, w0.z, acc[i][2]);
        acc[i][3] = fmaf(a4[i].x, w0.w, acc[i][3]);
        acc[i][0] = fmaf(a4[i].y, w1.x, acc[i][0]);
        acc[i][1] = fmaf(a4[i].y, w1.y, acc[i][1]);
        acc[i][2] = fmaf(a4[i].y, w1.z, acc[i][2]);
        acc[i][3] = fmaf(a4[i].y, w1.w, acc[i][3]);
        acc[i][0] = fmaf(a4[i].z, w2.x, acc[i][0]);
        acc[i][1] = fmaf(a4[i].z, w2.y, acc[i][1]);
        acc[i][2] = fmaf(a4[i].z, w2.z, acc[i][2]);
        acc[i][3] = fmaf(a4[i].z, w2.w, acc[i][3]);
        acc[i][0] = fmaf(a4[i].w, w3.x, acc[i][0]);
        acc[i][1] = fmaf(a4[i].w, w3.y, acc[i][1]);
        acc[i][2] = fmaf(a4[i].w, w3.z, acc[i][2]);
        acc[i][3] = fmaf(a4[i].w, w3.w, acc[i][3]);
      }
    }
    const int row0 = tile * TILE_M + rg * MR;
#pragma unroll
    for (int i = 0; i < MR; ++i) {
      int row = row0 + i;
      float v0 = acc[i][0], v1 = acc[i][1], v2 = acc[i][2], v3 = acc[i][3];
      if (NORM) {
        v0 = fmaxf(v0, 0.f); v1 = fmaxf(v1, 0.f);
        v2 = fmaxf(v2, 0.f); v3 = fmaxf(v3, 0.f);
        float s = v0 * v0 + v1 * v1 + v2 * v2 + v3 * v3;
#pragma unroll
        for (int off = JT / 2; off >= 1; off >>= 1) s += __shfl_xor(s, off, JT);
        float inv = 1.0f / fmaxf(sqrtf(s), 1e-12f);
        v0 *= inv; v1 *= inv; v2 *= inv; v3 *= inv;
      }
      if (row < n)
        ((float4*)(out + (size_t)row * OUT_DIM))[j] = make_float4(v0, v1, v2, v3);
    }
    __syncthreads();
  }
}

extern "C" void kernel_launch(void* const* d_in, const int* in_sizes, int n_in,
                              void* d_out, int out_size, void* d_ws, size_t ws_size,
                              hipStream_t stream) {
  const float* x  = (const float*)d_in[0];
  const int*   ei = (const int*)d_in[1];
  const float* C  = (const float*)d_in[2];
  const float* W1 = (const float*)d_in[3];
  const float* b1 = (const float*)d_in[4];
  const float* W2 = (const float*)d_in[5];
  const float* b2 = (const float*)d_in[6];
  const float* W3 = (const float*)d_in[7];
  const float* b3 = (const float*)d_in[8];
  float* out = (float*)d_out;

  // ---- workspace layout (fp16 pipeline) ----
  __half* prop16   = (__half*)d_ws;                    // NN*DIM
  __half* h16      = prop16 + (size_t)NN * DIM;        // NN*DIM (later g16)
  __half* x16      = h16 + (size_t)NN * DIM;           // NN*DIM (later hh16)
  __half* Wp1      = x16 + (size_t)NN * DIM;           // 16384
  __half* Wp2      = Wp1 + 16384;                      // 16384
  __half* Wp3      = Wp2 + 16384;                      // 8192
  int*    rowStart = (int*)(Wp3 + 8192);               // NN+2
  int*    cnt      = rowStart + NN + 2;                // NN
  int*    bsum     = cnt + NN;                         // 256
  int*    bbase    = bsum + 256;                       // 256
  int*    pos      = bbase + 256;                      // NE
  int2*   cv       = (int2*)(pos + NE);                // NE
  const size_t need = (size_t)(3 * NN * DIM) * 2 + 40960 * 2 +
                      (size_t)(2 * NN + 2 + 512) * 4 + (size_t)NE * 4 + (size_t)NE * 8;

  const dim3 blk(256);
  const int gEdge = (NE + 255) / 256;
  const int gTiles = (NN + 63) / 64;   // 782 blocks for gemm_mfma

  if (ws_size >= need) {
    // conversions / packing (independent of CSR build)
    f32_to_f16<<<(NN * DIM / 4 + 255) / 256, blk, 0, stream>>>(x, x16, NN * DIM / 4);
    pack_w<<<(16384 + 255) / 256, blk, 0, stream>>>(W1, Wp1, 128, 16384);
    pack_w<<<(16384 + 255) / 256, blk, 0, stream>>>(W2, Wp2, 128, 16384);
    pack_w<<<(8192 + 255) / 256, blk, 0, stream>>>(W3, Wp3, 64, 8192);

    // ---- build CSR once, reuse 3x ----
    hipMemsetAsync(cnt, 0, (size_t)NN * 4, stream);
    edge_histo_pos<<<gEdge, blk, 0, stream>>>(ei, cnt, pos);
    block_sums<<<NB, blk, 0, stream>>>(cnt, bsum);
    scan_bsums<<<1, blk, 0, stream>>>(bsum, bbase);
    scan_final<<<NB, blk, 0, stream>>>(cnt, bbase, rowStart);
    edge_scatter<<<gEdge, blk, 0, stream>>>(ei, C, rowStart, pos, cv);

    // layer 1: prop16 = C@x16; h16 = fp16(norm(relu(prop16@W1 + b1)))
    spmm_csr_h<128, false, true><<<(NN + 7) / 8, blk, 0, stream>>>(rowStart, cv, x16, nullptr, prop16);
    gemm_mfma<128, true, true><<<gTiles, blk, 0, stream>>>(prop16, Wp1, b1, h16, NN);
    // layer 2: prop16 = C@h16; hh16 = fp16(norm(relu(prop16@W2 + b2)))  (reuse x16)
    spmm_csr_h<128, false, true><<<(NN + 7) / 8, blk, 0, stream>>>(rowStart, cv, h16, nullptr, prop16);
    __half* hh16 = x16;
    gemm_mfma<128, true, true><<<gTiles, blk, 0, stream>>>(prop16, Wp2, b2, hh16, NN);
    // layer 3 reassociated: g16 = fp16(hh16@W3); out = C@g16 + b3  (reuse h16)
    __half* g16 = h16;
    gemm_mfma<64, false, false><<<gTiles, blk, 0, stream>>>(hh16, Wp3, nullptr, g16, NN);
    spmm_csr_h<64, true, false><<<(NN + 15) / 16, blk, 0, stream>>>(rowStart, cv, g16, b3, out);
  } else {
    // fallback: fp32 atomic path
    float* prop = (float*)d_ws;
    float* h    = prop + (size_t)NN * DIM;
    const size_t propBytes = (size_t)NN * DIM * sizeof(float);
    const int spmmGrid = 4096;
    hipMemsetAsync(prop, 0, propBytes, stream);
    spmm_atomic<<<spmmGrid, blk, 0, stream>>>(ei, C, x, prop);
    gemm_lds2<128, 4, true, true><<<512, blk, 0, stream>>>(prop, W1, b1, h, NN);
    hipMemsetAsync(prop, 0, propBytes, stream);
    spmm_atomic<<<spmmGrid, blk, 0, stream>>>(ei, C, h, prop);
    gemm_lds2<128, 4, true, true><<<512, blk, 0, stream>>>(prop, W2, b2, h, NN);
    hipMemsetAsync(prop, 0, propBytes, stream);
    spmm_atomic<<<spmmGrid, blk, 0, stream>>>(ei, C, h, prop);
    gemm_lds2<64, 2, false, true><<<768, blk, 0, stream>>>(prop, W3, b3, out, NN);
  }
}